// Round 10
// baseline (102.320 us; speedup 1.0000x reference)
//
#include <hip/hip_runtime.h>
#include <hip/hip_bf16.h>

#define LEN 4096
#define BATCH 32
#define CH 256
#define REPN 198
#define GHOSTN 58
#define NROW (REPN * BATCH)     /* 6336 */
#define NGHOST (GHOSTN * BATCH) /* 1856 */
#define P1REPBLK 1584           /* 6336 rep waves / 4 waves per block */

typedef float f32x4 __attribute__((ext_vector_type(4)));

// ---------------------------------------------------------------------------
// COMPILE-TIME numpy-legacy RNG replication (verified rounds 1-8):
// np.random.seed(123); np.random.choice(256, 58, replace=False)
// ---------------------------------------------------------------------------
struct MTState { unsigned mt[624]; int mti; };
struct Tab { int rep[REPN]; int ghost[GHOSTN]; };

static constexpr unsigned mt_next(MTState& s) {
    if (s.mti >= 624) {
        for (int k = 0; k < 624; ++k) {
            unsigned y = (s.mt[k] & 0x80000000u) | (s.mt[(k + 1) % 624] & 0x7fffffffu);
            s.mt[k] = s.mt[(k + 397) % 624] ^ (y >> 1) ^ ((y & 1u) ? 0x9908b0dfu : 0u);
        }
        s.mti = 0;
    }
    unsigned y = s.mt[s.mti++];
    y ^= y >> 11;
    y ^= (y << 7) & 0x9d2c5680u;
    y ^= (y << 15) & 0xefc60000u;
    y ^= y >> 18;
    return y;
}

static constexpr Tab make_tab() {
    MTState s{};
    s.mt[0] = 123u;
    for (int i = 1; i < 624; ++i)
        s.mt[i] = 1812433253u * (s.mt[i - 1] ^ (s.mt[i - 1] >> 30)) + (unsigned)i;
    s.mti = 624;
    int perm[256] = {};
    for (int i = 0; i < 256; ++i) perm[i] = i;
    for (int i = 255; i > 0; --i) {
        unsigned mask = (unsigned)i;
        mask |= mask >> 1; mask |= mask >> 2; mask |= mask >> 4;
        mask |= mask >> 8; mask |= mask >> 16;
        unsigned j = 0;
        do { j = mt_next(s) & mask; } while (j > (unsigned)i);
        int t = perm[i]; perm[i] = perm[j]; perm[j] = t;
    }
    bool g[256] = {};
    for (int k = 0; k < GHOSTN; ++k) g[perm[k]] = true;
    Tab t{};
    int rc = 0, gc = 0;
    for (int c = 0; c < 256; ++c) {
        if (g[c]) t.ghost[gc++] = c;
        else      t.rep[rc++] = c;
    }
    return t;
}

__constant__ Tab d_tab = make_tab();

// ===========================================================================
// Pass 1 (R10) — wave-per-row stats at CPT=16, register-direct windows.
// Ablation R6-R9 proved p1 insensitive to occupancy (4 vs 8 blk/CU) and
// pipeline depth (1 vs 2 windows): the binding term is STALL COUNT — 16
// sequential {5 loads -> vmcnt(0) -> compute} rounds per row at CPT=4.
// CPT=16: 4 rounds/row, 32 VMEM/row (vs 80), L1 amp 2x (vs 5x). Stats body
// is the verified R4 baseline STAT_BODY verbatim (same v[32] indexing:
// v[k] = row[l0-8+k]); only the window source moves from LDS to registers.
// Edge lanes: exactly (g==0,lane==0) and (g==3,lane==63).
//   blocks [0, 1584)      : 4 waves x 1 rep row each (stats only)
//   blocks [1584, 3440)   : ghost copy, one row per block
// FIR semantics (verified rounds 1-8):
//   x1 group i: taps v[j+1+3i..j+3+3i], gated on 0 <= l-6+3i < LEN
//   x2 group i: taps v[j+13-3i..j+15-3i], gated on 0 <= l+6-3i < LEN
//   x3 = ungated group-2 partial of x1 (= the shared middle 3-tap)
// ===========================================================================
__global__ __launch_bounds__(256) void pass1_kernel(const float* __restrict__ x,
                                                    const float* __restrict__ w1,
                                                    const float* __restrict__ w2,
                                                    float* __restrict__ stats_ws,
                                                    float* __restrict__ out) {
    const int blk = blockIdx.x;
    if (blk >= P1REPBLK) {
        // ghost pass-through: NT load (never re-read), plain store
        const int g = (blk - P1REPBLK) % GHOSTN;
        const int b = (blk - P1REPBLK) / GHOSTN;
        const int ch = d_tab.ghost[g];
        const f32x4* src = (const f32x4*)(x + ((size_t)b * CH + ch) * LEN);
        f32x4* dst = (f32x4*)(out + ((size_t)b * CH + REPN + g) * LEN);
#pragma unroll
        for (int k = 0; k < 4; ++k) {
            f32x4 t = __builtin_nontemporal_load(&src[threadIdx.x + 256 * k]);
            dst[threadIdx.x + 256 * k] = t;
        }
        return;
    }

    const int wv = (blk << 2) | (threadIdx.x >> 6);
    const int lane = threadIdx.x & 63;
    const int r = wv % REPN;
    const int b = wv / REPN;
    const float* row = x + ((size_t)b * CH + d_tab.rep[r]) * LEN;

    float wb[5][3];
    {
        const float* p1 = w1 + r * 15;
        const float* p2 = w2 + r * 15;
#pragma unroll
        for (int i = 0; i < 5; ++i)
#pragma unroll
            for (int t = 0; t < 3; ++t) wb[i][t] = p1[i * 3 + t] + p2[i * 3 + t];
    }

    float s1 = 0, s1q = 0, s2 = 0, s2q = 0, s3 = 0, s3q = 0;
    float v[32];

// Interior 16-output body: ungated, shared middle group m (= x3).
#define STAT16_FAST(V)                                                            \
    {                                                                             \
        _Pragma("unroll")                                                         \
        for (int j = 0; j < 16; ++j) {                                            \
            float m  = fmaf(wb[2][0], V[j + 7],                                   \
                       fmaf(wb[2][1], V[j + 8],  wb[2][2] * V[j + 9]));           \
            float l0g = fmaf(wb[0][0], V[j + 1],                                  \
                        fmaf(wb[0][1], V[j + 2],  wb[0][2] * V[j + 3]));          \
            float l1g = fmaf(wb[1][0], V[j + 4],                                  \
                        fmaf(wb[1][1], V[j + 5],  wb[1][2] * V[j + 6]));          \
            float h3 = fmaf(wb[3][0], V[j + 10],                                  \
                       fmaf(wb[3][1], V[j + 11], wb[3][2] * V[j + 12]));          \
            float h4 = fmaf(wb[4][0], V[j + 13],                                  \
                       fmaf(wb[4][1], V[j + 14], wb[4][2] * V[j + 15]));          \
            float q0 = fmaf(wb[4][0], V[j + 1],                                   \
                       fmaf(wb[4][1], V[j + 2],  wb[4][2] * V[j + 3]));           \
            float q1 = fmaf(wb[3][0], V[j + 4],                                   \
                       fmaf(wb[3][1], V[j + 5],  wb[3][2] * V[j + 6]));           \
            float p3 = fmaf(wb[1][0], V[j + 10],                                  \
                       fmaf(wb[1][1], V[j + 11], wb[1][2] * V[j + 12]));          \
            float p4 = fmaf(wb[0][0], V[j + 13],                                  \
                       fmaf(wb[0][1], V[j + 14], wb[0][2] * V[j + 15]));          \
            float x1 = ((l0g + l1g) + m) + (h3 + h4);                             \
            float x2 = ((q0 + q1) + m) + (p3 + p4);                               \
            s1 += x1; s1q = fmaf(x1, x1, s1q);                                    \
            s2 += x2; s2q = fmaf(x2, x2, s2q);                                    \
            s3 += m;  s3q = fmaf(m, m, s3q);                                      \
        }                                                                         \
    }

// Edge 16-output body: verbatim gated group-wise form (R4-proven).
#define STAT16_EDGE(L0, V)                                                        \
    {                                                                             \
        _Pragma("unroll")                                                         \
        for (int j = 0; j < 16; ++j) {                                            \
            const int l = (L0) + j;                                               \
            float x1 = 0.f, x2 = 0.f, x3 = 0.f;                                   \
            _Pragma("unroll")                                                     \
            for (int i = 0; i < 5; ++i) {                                         \
                float a1 = fmaf(wb[i][0], V[j + 1 + 3 * i],                       \
                           fmaf(wb[i][1], V[j + 2 + 3 * i],                       \
                                wb[i][2] * V[j + 3 + 3 * i]));                    \
                float a2 = fmaf(wb[i][0], V[j + 13 - 3 * i],                      \
                           fmaf(wb[i][1], V[j + 14 - 3 * i],                      \
                                wb[i][2] * V[j + 15 - 3 * i]));                   \
                if (i == 2) x3 = a1; /* ungated */                                \
                a1 = ((unsigned)(l - 6 + 3 * i) < (unsigned)LEN) ? a1 : 0.f;      \
                a2 = ((unsigned)(l + 6 - 3 * i) < (unsigned)LEN) ? a2 : 0.f;      \
                x1 += a1; x2 += a2;                                               \
            }                                                                     \
            s1 += x1; s1q = fmaf(x1, x1, s1q);                                    \
            s2 += x2; s2q = fmaf(x2, x2, s2q);                                    \
            s3 += x3; s3q = fmaf(x3, x3, s3q);                                    \
        }                                                                         \
    }

#pragma unroll 1
    for (int g = 0; g < 4; ++g) {
        const int l0 = g * 1024 + lane * 16;
        const bool edge = (g == 0 && lane == 0) || (g == 3 && lane == 63);
        if (!edge) {
            // register-direct window: v[k] = row[l0 - 8 + k], 8x dwordx4.
            const f32x4* q4 = (const f32x4*)(row + l0 - 8);
#pragma unroll
            for (int t = 0; t < 8; ++t) {
                f32x4 u = q4[t];
                v[4 * t] = u.x; v[4 * t + 1] = u.y;
                v[4 * t + 2] = u.z; v[4 * t + 3] = u.w;
            }
            STAT16_FAST(v);
        } else {
            // bounds-checked window (zeros outside row) + gated body.
#pragma unroll
            for (int d = 0; d < 32; ++d) {
                int fi = l0 - 8 + d;
                v[d] = ((unsigned)fi < (unsigned)LEN) ? row[fi] : 0.f;
            }
            STAT16_EDGE(l0, v);
        }
    }
#undef STAT16_FAST
#undef STAT16_EDGE

    // wave reduce (64 lanes) -> lane 0 writes 6 partials for (r, b)
#pragma unroll
    for (int off = 32; off > 0; off >>= 1) {
        s1 += __shfl_down(s1, off);  s1q += __shfl_down(s1q, off);
        s2 += __shfl_down(s2, off);  s2q += __shfl_down(s2q, off);
        s3 += __shfl_down(s3, off);  s3q += __shfl_down(s3q, off);
    }
    if (lane == 0) {
        stats_ws[(0 * REPN + r) * BATCH + b] = s1;
        stats_ws[(1 * REPN + r) * BATCH + b] = s1q;
        stats_ws[(2 * REPN + r) * BATCH + b] = s2;
        stats_ws[(3 * REPN + r) * BATCH + b] = s2q;
        stats_ws[(4 * REPN + r) * BATCH + b] = s3;
        stats_ws[(5 * REPN + r) * BATCH + b] = s3q;
    }
}

// ===========================================================================
// Pass 2 — barrier-free wave-per-row, rep rows ONLY (unchanged from R4/R6).
// ===========================================================================
__device__ __forceinline__ void load_fast(const float* __restrict__ row, int e, float* v) {
    const f32x4* q4 = (const f32x4*)(row + e - 8);
#pragma unroll
    for (int t = 0; t < 5; ++t) {
        f32x4 u = q4[t];
        v[4 * t] = u.x; v[4 * t + 1] = u.y; v[4 * t + 2] = u.z; v[4 * t + 3] = u.w;
    }
}

__device__ __forceinline__ void load_slow(const float* __restrict__ row, int e, float* v) {
#pragma unroll
    for (int d = 0; d < 20; ++d) {
        int fi = e - 8 + d;
        v[d] = ((unsigned)fi < (unsigned)LEN) ? row[fi] : 0.f;
    }
}

__global__ __launch_bounds__(256) void pass2_kernel(const float* __restrict__ x,
                                                    const float* __restrict__ w1,
                                                    const float* __restrict__ w2,
                                                    const float* __restrict__ stats_ws,
                                                    const float* __restrict__ g1, const float* __restrict__ b1,
                                                    const float* __restrict__ g2, const float* __restrict__ b2,
                                                    const float* __restrict__ g3, const float* __restrict__ b3,
                                                    float* __restrict__ out) {
    const int wv = (blockIdx.x << 2) | (threadIdx.x >> 6);
    const int lane = threadIdx.x & 63;
    const int r = wv % REPN;
    const int b = wv / REPN;
    const int ch = d_tab.rep[r];
    const float* row = x + ((size_t)b * CH + ch) * LEN;

    // BN finalize: lanes load the 32 batch partials (dup across halves), butterfly.
    float p[6];
    const int bb = lane & 31;
#pragma unroll
    for (int q = 0; q < 6; ++q) p[q] = stats_ws[(q * REPN + r) * BATCH + bb];
#pragma unroll
    for (int m = 1; m < 32; m <<= 1)
#pragma unroll
        for (int q = 0; q < 6; ++q) p[q] += __shfl_xor(p[q], m);

    const double invN = 1.0 / (double)(BATCH * LEN);
    float sc[3], sh[3];
    {
        const float gr[3] = {g1[r], g2[r], g3[r]};
        const float br[3] = {b1[r], b2[r], b3[r]};
#pragma unroll
        for (int q = 0; q < 3; ++q) {
            double mean = (double)p[2 * q] * invN;
            double var = (double)p[2 * q + 1] * invN - mean * mean;
            double inv = 1.0 / sqrt(var + 1e-5);
            double scale = (double)gr[q] * inv;
            sc[q] = (float)scale;
            sh[q] = (float)((double)br[q] - mean * scale);
        }
    }
    const float base = sh[0] + sh[1] + sh[2];

    float wb[5][3];
    const float* p1 = w1 + r * 15;
    const float* p2 = w2 + r * 15;
#pragma unroll
    for (int i = 0; i < 5; ++i)
#pragma unroll
        for (int t = 0; t < 3; ++t) wb[i][t] = p1[i * 3 + t] + p2[i * 3 + t];

    // Combined 15-tap filter (interior): tap d=3k+t applies to v[j+1+d].
    float c[15];
#pragma unroll
    for (int k = 0; k < 5; ++k)
#pragma unroll
        for (int t = 0; t < 3; ++t)
            c[3 * k + t] = fmaf(sc[0], wb[k][t], sc[1] * wb[4 - k][t]);
#pragma unroll
    for (int t = 0; t < 3; ++t) c[6 + t] = fmaf(sc[2], wb[2][t], c[6 + t]);

    float* orow = out + ((size_t)b * CH + r) * LEN;
    float v[20];

#define INTERIOR_QUAD(E)                                                          \
    {                                                                             \
        float o[4];                                                               \
        _Pragma("unroll")                                                         \
        for (int j = 0; j < 4; ++j) {                                             \
            float acc = base + v[j + 8];                                          \
            _Pragma("unroll")                                                     \
            for (int d = 0; d < 15; ++d) acc = fmaf(c[d], v[j + 1 + d], acc);     \
            o[j] = acc;                                                           \
        }                                                                         \
        f32x4 t = {o[0], o[1], o[2], o[3]};                                       \
        *(f32x4*)(orow + (E)) = t;                                                \
    }

#define EDGE_QUAD(E)                                                              \
    {                                                                             \
        float o[4];                                                               \
        _Pragma("unroll")                                                         \
        for (int j = 0; j < 4; ++j) {                                             \
            const int l = (E) + j;                                                \
            float x1 = 0.f, x2 = 0.f, x3 = 0.f;                                   \
            _Pragma("unroll")                                                     \
            for (int i = 0; i < 5; ++i) {                                         \
                float a1 = fmaf(wb[i][0], v[j + 1 + 3 * i],                       \
                           fmaf(wb[i][1], v[j + 2 + 3 * i],                       \
                                wb[i][2] * v[j + 3 + 3 * i]));                    \
                float a2 = fmaf(wb[i][0], v[j + 13 - 3 * i],                      \
                           fmaf(wb[i][1], v[j + 14 - 3 * i],                      \
                                wb[i][2] * v[j + 15 - 3 * i]));                   \
                if (i == 2) x3 = a1;                                              \
                a1 = ((unsigned)(l - 6 + 3 * i) < (unsigned)LEN) ? a1 : 0.f;      \
                a2 = ((unsigned)(l + 6 - 3 * i) < (unsigned)LEN) ? a2 : 0.f;      \
                x1 += a1; x2 += a2;                                               \
            }                                                                     \
            o[j] = fmaf(sc[0], x1, fmaf(sc[1], x2, fmaf(sc[2], x3, base + v[j + 8]))); \
        }                                                                         \
        f32x4 t = {o[0], o[1], o[2], o[3]};                                       \
        *(f32x4*)(orow + (E)) = t;                                                \
    }

    { // k = 0
        const int e = 4 * lane;
        if (lane < 2) { load_slow(row, e, v); EDGE_QUAD(e); }
        else          { load_fast(row, e, v); INTERIOR_QUAD(e); }
    }
#pragma unroll
    for (int k = 1; k < 15; ++k) {
        const int e = 4 * lane + 256 * k;
        load_fast(row, e, v);
        INTERIOR_QUAD(e);
    }
    { // k = 15
        const int e = 4 * lane + 3840;
        if (lane >= 62) { load_slow(row, e, v); EDGE_QUAD(e); }
        else            { load_fast(row, e, v); INTERIOR_QUAD(e); }
    }
#undef INTERIOR_QUAD
#undef EDGE_QUAD
}

extern "C" void kernel_launch(void* const* d_in, const int* in_sizes, int n_in,
                              void* d_out, int out_size, void* d_ws, size_t ws_size,
                              hipStream_t stream) {
    const float* x  = (const float*)d_in[0];
    const float* w1 = (const float*)d_in[1];
    const float* w2 = (const float*)d_in[2];
    const float* g1 = (const float*)d_in[3];
    const float* b1 = (const float*)d_in[4];
    const float* g2 = (const float*)d_in[5];
    const float* b2 = (const float*)d_in[6];
    const float* g3 = (const float*)d_in[7];
    const float* b3 = (const float*)d_in[8];
    float* out = (float*)d_out;
    float* stats_ws = (float*)d_ws;   // 6*198*32 floats = 152 KB

    // pass1: 1584 rep-stats blocks (wave-per-row, CPT=16 register windows)
    //        + 1856 ghost copy blocks.
    pass1_kernel<<<P1REPBLK + NGHOST, 256, 0, stream>>>(x, w1, w2, stats_ws, out);
    // pass2: 6336 rep waves = 1584 blocks (barrier-free, plain stores).
    pass2_kernel<<<1584, 256, 0, stream>>>(x, w1, w2, stats_ws,
                                           g1, b1, g2, b2, g3, b3, out);
}

// Round 11
// 85.977 us; speedup vs baseline: 1.1901x; 1.1901x over previous
//
#include <hip/hip_runtime.h>

#define LEN 4096
#define BATCH 32
#define CH 256
#define REPN 198
#define GHOSTN 58
#define NROW (REPN * BATCH)     /* 6336 */
#define NGHOST (GHOSTN * BATCH) /* 1856 */
#define P1REPBLK 1584           /* 6336 rep waves / 4 waves per block */

typedef float f32x4 __attribute__((ext_vector_type(4)));

// ---------------------------------------------------------------------------
// COMPILE-TIME numpy-legacy RNG replication (verified rounds 1-8):
// np.random.seed(123); np.random.choice(256, 58, replace=False)
// ---------------------------------------------------------------------------
struct MTState { unsigned mt[624]; int mti; };
struct Tab { int rep[REPN]; int ghost[GHOSTN]; };

static constexpr unsigned mt_next(MTState& s) {
    if (s.mti >= 624) {
        for (int k = 0; k < 624; ++k) {
            unsigned y = (s.mt[k] & 0x80000000u) | (s.mt[(k + 1) % 624] & 0x7fffffffu);
            s.mt[k] = s.mt[(k + 397) % 624] ^ (y >> 1) ^ ((y & 1u) ? 0x9908b0dfu : 0u);
        }
        s.mti = 0;
    }
    unsigned y = s.mt[s.mti++];
    y ^= y >> 11;
    y ^= (y << 7) & 0x9d2c5680u;
    y ^= (y << 15) & 0xefc60000u;
    y ^= y >> 18;
    return y;
}

static constexpr Tab make_tab() {
    MTState s{};
    s.mt[0] = 123u;
    for (int i = 1; i < 624; ++i)
        s.mt[i] = 1812433253u * (s.mt[i - 1] ^ (s.mt[i - 1] >> 30)) + (unsigned)i;
    s.mti = 624;
    int perm[256] = {};
    for (int i = 0; i < 256; ++i) perm[i] = i;
    for (int i = 255; i > 0; --i) {
        unsigned mask = (unsigned)i;
        mask |= mask >> 1; mask |= mask >> 2; mask |= mask >> 4;
        mask |= mask >> 8; mask |= mask >> 16;
        unsigned j = 0;
        do { j = mt_next(s) & mask; } while (j > (unsigned)i);
        int t = perm[i]; perm[i] = perm[j]; perm[j] = t;
    }
    bool g[256] = {};
    for (int k = 0; k < GHOSTN; ++k) g[perm[k]] = true;
    Tab t{};
    int rc = 0, gc = 0;
    for (int c = 0; c < 256; ++c) {
        if (g[c]) t.ghost[gc++] = c;
        else      t.rep[rc++] = c;
    }
    return t;
}

__constant__ Tab d_tab = make_tab();

// c1[d] = wb[d/3][d%3] (x1 filter, offsets d-7); c2[d] = wb[4-d/3][d%3]
// (x2 = group-reversed filter, same offsets). Verified mapping:
//   x1[l] = sum_d c1[d] x[l+d-7], group i = d/3 gated on 0 <= l-6+3i < LEN
//   x2[l] = sum_d c2[d] x[l+d-7], tap-d gate is the SAME (l-6+3*(d/3))
//   x3[l] = middle 3-tap (d = 6..8 of c1), ungated.
#define C1F(D) wb[(D) / 3][(D) % 3]
#define C2F(D) wb[4 - (D) / 3][(D) % 3]

// ===========================================================================
// Pass 1 (R11) — AUTOCORRELATION stats. All six BN sums derive from the
// row's autocorrelation A[0..14] and Sx:
//   sum_all y   = (sum c) * Sx
//   sum_all y^2 = rho[0]A[0] + 2 sum_{d=1..14} rho[d]A[d], rho[d]=sum c c_+d
// valid over ALL l in Z (zero-padded). Gated actual sums = identity sums
// + corrections on l in [-7,5] u [4090,4102] (computed one output per lane,
// lanes 0..25, with the VERIFIED gate logic). Interior l in [6,4089] is
// exactly gated==ungated (all gates open, zero-pad shared).
// Per elem: 16 FMA (vs 41). Per lane: 20 dwordx4/row (vs 80), disjoint
// 64-float chunk + right halo, double-buffered B0/B1 (16 regs each).
//   blocks [0, 1584)      : 4 waves x 1 rep row each (stats only)
//   blocks [1584, 3440)   : ghost copy, one row per block
// ===========================================================================
__global__ __launch_bounds__(256) void pass1_kernel(const float* __restrict__ x,
                                                    const float* __restrict__ w1,
                                                    const float* __restrict__ w2,
                                                    float* __restrict__ stats_ws,
                                                    float* __restrict__ out) {
    const int blk = blockIdx.x;
    if (blk >= P1REPBLK) {
        // ghost pass-through: NT load (never re-read), plain store
        const int g = (blk - P1REPBLK) % GHOSTN;
        const int b = (blk - P1REPBLK) / GHOSTN;
        const int ch = d_tab.ghost[g];
        const f32x4* src = (const f32x4*)(x + ((size_t)b * CH + ch) * LEN);
        f32x4* dst = (f32x4*)(out + ((size_t)b * CH + REPN + g) * LEN);
#pragma unroll
        for (int k = 0; k < 4; ++k) {
            f32x4 t = __builtin_nontemporal_load(&src[threadIdx.x + 256 * k]);
            dst[threadIdx.x + 256 * k] = t;
        }
        return;
    }

    const int wv = (blk << 2) | (threadIdx.x >> 6);
    const int lane = threadIdx.x & 63;
    const int r = wv % REPN;
    const int b = wv / REPN;
    const float* row = x + ((size_t)b * CH + d_tab.rep[r]) * LEN;

    // ---- main accumulation: A[0..14], Sx over this lane's 64 elements ----
    float A[15];
#pragma unroll
    for (int dl = 0; dl < 15; ++dl) A[dl] = 0.f;
    float SX = 0.f;
    float B0[16], B1[16];
    const int base = lane << 6;

#define LOADV16(DST, OFF)                                                         \
    {                                                                             \
        if ((OFF) < LEN) {                                                        \
            const f32x4* q4_ = (const f32x4*)(row + (OFF));                       \
            _Pragma("unroll")                                                     \
            for (int t = 0; t < 4; ++t) {                                         \
                f32x4 u_ = q4_[t];                                                \
                DST[4 * t] = u_.x; DST[4 * t + 1] = u_.y;                         \
                DST[4 * t + 2] = u_.z; DST[4 * t + 3] = u_.w;                     \
            }                                                                     \
        } else {                                                                  \
            _Pragma("unroll")                                                     \
            for (int t = 0; t < 16; ++t) DST[t] = 0.f;                            \
        }                                                                         \
    }

// A[dl] += x[u] * x[u+dl] for u = chunk's 16 elements; window = LO ++ HI[0..13]
#define ACC16(LO, HI)                                                             \
    {                                                                             \
        _Pragma("unroll")                                                         \
        for (int j = 0; j < 16; ++j) {                                            \
            const float xj_ = LO[j];                                              \
            SX += xj_;                                                            \
            _Pragma("unroll")                                                     \
            for (int dl = 0; dl < 15; ++dl) {                                     \
                const float xd_ = (j + dl < 16) ? LO[j + dl] : HI[j + dl - 16];   \
                A[dl] = fmaf(xj_, xd_, A[dl]);                                    \
            }                                                                     \
        }                                                                         \
    }

    LOADV16(B0, base);
    LOADV16(B1, base + 16);
    ACC16(B0, B1);                 // u in [base, base+16)
    LOADV16(B0, base + 32);
    ACC16(B1, B0);                 // u in [base+16, base+32)
    LOADV16(B1, base + 48);
    ACC16(B0, B1);                 // u in [base+32, base+48)
    LOADV16(B0, base + 64);        // OOB-zero only for lane 63
    ACC16(B1, B0);                 // u in [base+48, base+64)
#undef LOADV16
#undef ACC16

    // ---- weights (needed only from here on; keeps main-loop VGPR low) ----
    float wb[5][3];
    {
        const float* p1 = w1 + r * 15;
        const float* p2 = w2 + r * 15;
#pragma unroll
        for (int i = 0; i < 5; ++i)
#pragma unroll
            for (int t = 0; t < 3; ++t) wb[i][t] = p1[i * 3 + t] + p2[i * 3 + t];
    }

    // ---- boundary corrections: one output l per lane, lanes 0..25 ----
    // lanes 0..12  -> l = lane - 7      in [-7, 5]   (left)
    // lanes 13..25 -> l = 4090+lane-13  in [4090, 4102] (right)
    // out-of-range l: subtract ungated u1,u2,u3 (identity includes them);
    // in-range edge l: add (gated - ungated) for x1,x2 (x3 has no gating).
    float d1 = 0.f, d1q = 0.f, d2 = 0.f, d2q = 0.f, d3 = 0.f, d3q = 0.f;
    if (lane < 26) {
        const int l = (lane <= 12) ? (lane - 7) : (4090 + (lane - 13));
        float u1 = 0.f, u2 = 0.f, u3 = 0.f, g1 = 0.f, g2 = 0.f;
#pragma unroll
        for (int d = 0; d < 15; ++d) {
            const int p = l + d - 7;
            const float xd = ((unsigned)p < (unsigned)LEN) ? row[p] : 0.f;
            const float a1 = C1F(d) * xd;
            const float a2 = C2F(d) * xd;
            u1 += a1; u2 += a2;
            if (d >= 6 && d <= 8) u3 += a1;          // middle group = x3
            const bool gate = ((unsigned)(l - 6 + 3 * (d / 3)) < (unsigned)LEN);
            g1 += gate ? a1 : 0.f;
            g2 += gate ? a2 : 0.f;
        }
        if ((unsigned)l < (unsigned)LEN) {
            d1 = g1 - u1;  d1q = fmaf(g1, g1, -u1 * u1);
            d2 = g2 - u2;  d2q = fmaf(g2, g2, -u2 * u2);
            /* x3: gated == ungated in range -> no delta */
        } else {
            d1 = -u1;  d1q = -u1 * u1;
            d2 = -u2;  d2q = -u2 * u2;
            d3 = -u3;  d3q = -u3 * u3;
        }
    }

    // ---- wave reduce: A[15], SX, deltas[6] ----
#pragma unroll
    for (int off = 32; off > 0; off >>= 1) {
#pragma unroll
        for (int dl = 0; dl < 15; ++dl) A[dl] += __shfl_down(A[dl], off);
        SX += __shfl_down(SX, off);
        d1 += __shfl_down(d1, off);   d1q += __shfl_down(d1q, off);
        d2 += __shfl_down(d2, off);   d2q += __shfl_down(d2q, off);
        d3 += __shfl_down(d3, off);   d3q += __shfl_down(d3q, off);
    }

    if (lane == 0) {
        // rho-weighted autocorr sums (delta loop unrolled, wb refs static)
        float sq1 = 0.f, sq2 = 0.f;
#pragma unroll
        for (int dl = 0; dl < 15; ++dl) {
            float r1 = 0.f, r2 = 0.f;
#pragma unroll
            for (int d = 0; d + dl < 15; ++d) {
                r1 = fmaf(C1F(d), C1F(d + dl), r1);
                r2 = fmaf(C2F(d), C2F(d + dl), r2);
            }
            const float wA = (dl ? 2.f : 1.f) * A[dl];
            sq1 = fmaf(r1, wA, sq1);
            sq2 = fmaf(r2, wA, sq2);
        }
        const float c30 = wb[2][0], c31 = wb[2][1], c32 = wb[2][2];
        float sq3 = (c30 * c30 + c31 * c31 + c32 * c32) * A[0]
                  + 2.f * (c30 * c31 + c31 * c32) * A[1]
                  + 2.f * (c30 * c32) * A[2];
        float cs = 0.f;
#pragma unroll
        for (int i = 0; i < 5; ++i)
#pragma unroll
            for (int t = 0; t < 3; ++t) cs += wb[i][t];
        const float c3s = c30 + c31 + c32;

        stats_ws[(0 * REPN + r) * BATCH + b] = fmaf(cs, SX, d1);
        stats_ws[(1 * REPN + r) * BATCH + b] = sq1 + d1q;
        stats_ws[(2 * REPN + r) * BATCH + b] = fmaf(cs, SX, d2);   // sum(c2)==sum(c1)
        stats_ws[(3 * REPN + r) * BATCH + b] = sq2 + d2q;
        stats_ws[(4 * REPN + r) * BATCH + b] = fmaf(c3s, SX, d3);
        stats_ws[(5 * REPN + r) * BATCH + b] = sq3 + d3q;
    }
}

// ===========================================================================
// Pass 2 — barrier-free wave-per-row, rep rows ONLY (unchanged from R4/R6).
// ===========================================================================
__device__ __forceinline__ void load_fast(const float* __restrict__ row, int e, float* v) {
    const f32x4* q4 = (const f32x4*)(row + e - 8);
#pragma unroll
    for (int t = 0; t < 5; ++t) {
        f32x4 u = q4[t];
        v[4 * t] = u.x; v[4 * t + 1] = u.y; v[4 * t + 2] = u.z; v[4 * t + 3] = u.w;
    }
}

__device__ __forceinline__ void load_slow(const float* __restrict__ row, int e, float* v) {
#pragma unroll
    for (int d = 0; d < 20; ++d) {
        int fi = e - 8 + d;
        v[d] = ((unsigned)fi < (unsigned)LEN) ? row[fi] : 0.f;
    }
}

__global__ __launch_bounds__(256) void pass2_kernel(const float* __restrict__ x,
                                                    const float* __restrict__ w1,
                                                    const float* __restrict__ w2,
                                                    const float* __restrict__ stats_ws,
                                                    const float* __restrict__ g1, const float* __restrict__ b1,
                                                    const float* __restrict__ g2, const float* __restrict__ b2,
                                                    const float* __restrict__ g3, const float* __restrict__ b3,
                                                    float* __restrict__ out) {
    const int wv = (blockIdx.x << 2) | (threadIdx.x >> 6);
    const int lane = threadIdx.x & 63;
    const int r = wv % REPN;
    const int b = wv / REPN;
    const int ch = d_tab.rep[r];
    const float* row = x + ((size_t)b * CH + ch) * LEN;

    // BN finalize: lanes load the 32 batch partials (dup across halves), butterfly.
    float p[6];
    const int bb = lane & 31;
#pragma unroll
    for (int q = 0; q < 6; ++q) p[q] = stats_ws[(q * REPN + r) * BATCH + bb];
#pragma unroll
    for (int m = 1; m < 32; m <<= 1)
#pragma unroll
        for (int q = 0; q < 6; ++q) p[q] += __shfl_xor(p[q], m);

    const double invN = 1.0 / (double)(BATCH * LEN);
    float sc[3], sh[3];
    {
        const float gr[3] = {g1[r], g2[r], g3[r]};
        const float br[3] = {b1[r], b2[r], b3[r]};
#pragma unroll
        for (int q = 0; q < 3; ++q) {
            double mean = (double)p[2 * q] * invN;
            double var = (double)p[2 * q + 1] * invN - mean * mean;
            double inv = 1.0 / sqrt(var + 1e-5);
            double scale = (double)gr[q] * inv;
            sc[q] = (float)scale;
            sh[q] = (float)((double)br[q] - mean * scale);
        }
    }
    const float base = sh[0] + sh[1] + sh[2];

    float wb[5][3];
    const float* p1 = w1 + r * 15;
    const float* p2 = w2 + r * 15;
#pragma unroll
    for (int i = 0; i < 5; ++i)
#pragma unroll
        for (int t = 0; t < 3; ++t) wb[i][t] = p1[i * 3 + t] + p2[i * 3 + t];

    // Combined 15-tap filter (interior): tap d=3k+t applies to v[j+1+d].
    float c[15];
#pragma unroll
    for (int k = 0; k < 5; ++k)
#pragma unroll
        for (int t = 0; t < 3; ++t)
            c[3 * k + t] = fmaf(sc[0], wb[k][t], sc[1] * wb[4 - k][t]);
#pragma unroll
    for (int t = 0; t < 3; ++t) c[6 + t] = fmaf(sc[2], wb[2][t], c[6 + t]);

    float* orow = out + ((size_t)b * CH + r) * LEN;
    float v[20];

#define INTERIOR_QUAD(E)                                                          \
    {                                                                             \
        float o[4];                                                               \
        _Pragma("unroll")                                                         \
        for (int j = 0; j < 4; ++j) {                                             \
            float acc = base + v[j + 8];                                          \
            _Pragma("unroll")                                                     \
            for (int d = 0; d < 15; ++d) acc = fmaf(c[d], v[j + 1 + d], acc);     \
            o[j] = acc;                                                           \
        }                                                                         \
        f32x4 t = {o[0], o[1], o[2], o[3]};                                       \
        *(f32x4*)(orow + (E)) = t;                                                \
    }

#define EDGE_QUAD(E)                                                              \
    {                                                                             \
        float o[4];                                                               \
        _Pragma("unroll")                                                         \
        for (int j = 0; j < 4; ++j) {                                             \
            const int l = (E) + j;                                                \
            float x1 = 0.f, x2 = 0.f, x3 = 0.f;                                   \
            _Pragma("unroll")                                                     \
            for (int i = 0; i < 5; ++i) {                                         \
                float a1 = fmaf(wb[i][0], v[j + 1 + 3 * i],                       \
                           fmaf(wb[i][1], v[j + 2 + 3 * i],                       \
                                wb[i][2] * v[j + 3 + 3 * i]));                    \
                float a2 = fmaf(wb[i][0], v[j + 13 - 3 * i],                      \
                           fmaf(wb[i][1], v[j + 14 - 3 * i],                      \
                                wb[i][2] * v[j + 15 - 3 * i]));                   \
                if (i == 2) x3 = a1;                                              \
                a1 = ((unsigned)(l - 6 + 3 * i) < (unsigned)LEN) ? a1 : 0.f;      \
                a2 = ((unsigned)(l + 6 - 3 * i) < (unsigned)LEN) ? a2 : 0.f;      \
                x1 += a1; x2 += a2;                                               \
            }                                                                     \
            o[j] = fmaf(sc[0], x1, fmaf(sc[1], x2, fmaf(sc[2], x3, base + v[j + 8]))); \
        }                                                                         \
        f32x4 t = {o[0], o[1], o[2], o[3]};                                       \
        *(f32x4*)(orow + (E)) = t;                                                \
    }

    { // k = 0
        const int e = 4 * lane;
        if (lane < 2) { load_slow(row, e, v); EDGE_QUAD(e); }
        else          { load_fast(row, e, v); INTERIOR_QUAD(e); }
    }
#pragma unroll
    for (int k = 1; k < 15; ++k) {
        const int e = 4 * lane + 256 * k;
        load_fast(row, e, v);
        INTERIOR_QUAD(e);
    }
    { // k = 15
        const int e = 4 * lane + 3840;
        if (lane >= 62) { load_slow(row, e, v); EDGE_QUAD(e); }
        else            { load_fast(row, e, v); INTERIOR_QUAD(e); }
    }
#undef INTERIOR_QUAD
#undef EDGE_QUAD
}

extern "C" void kernel_launch(void* const* d_in, const int* in_sizes, int n_in,
                              void* d_out, int out_size, void* d_ws, size_t ws_size,
                              hipStream_t stream) {
    const float* x  = (const float*)d_in[0];
    const float* w1 = (const float*)d_in[1];
    const float* w2 = (const float*)d_in[2];
    const float* g1 = (const float*)d_in[3];
    const float* b1 = (const float*)d_in[4];
    const float* g2 = (const float*)d_in[5];
    const float* b2 = (const float*)d_in[6];
    const float* g3 = (const float*)d_in[7];
    const float* b3 = (const float*)d_in[8];
    float* out = (float*)d_out;
    float* stats_ws = (float*)d_ws;   // 6*198*32 floats = 152 KB

    // pass1: 1584 rep-stats blocks (autocorrelation wave-per-row)
    //        + 1856 ghost copy blocks.
    pass1_kernel<<<P1REPBLK + NGHOST, 256, 0, stream>>>(x, w1, w2, stats_ws, out);
    // pass2: 6336 rep waves = 1584 blocks (barrier-free, plain stores).
    pass2_kernel<<<1584, 256, 0, stream>>>(x, w1, w2, stats_ws,
                                           g1, b1, g2, b2, g3, b3, out);
}

// Round 12
// 85.462 us; speedup vs baseline: 1.1973x; 1.0060x over previous
//
#include <hip/hip_runtime.h>

#define LEN 4096
#define BATCH 32
#define CH 256
#define REPN 198
#define GHOSTN 58
#define NROW (REPN * BATCH)     /* 6336 */
#define NGHOST (GHOSTN * BATCH) /* 1856 */
#define P1REPBLK 1584           /* 6336 rep waves / 4 waves per block */

typedef float f32x4 __attribute__((ext_vector_type(4)));

// ---------------------------------------------------------------------------
// COMPILE-TIME numpy-legacy RNG replication (verified rounds 1-8):
// np.random.seed(123); np.random.choice(256, 58, replace=False)
// ---------------------------------------------------------------------------
struct MTState { unsigned mt[624]; int mti; };
struct Tab { int rep[REPN]; int ghost[GHOSTN]; };

static constexpr unsigned mt_next(MTState& s) {
    if (s.mti >= 624) {
        for (int k = 0; k < 624; ++k) {
            unsigned y = (s.mt[k] & 0x80000000u) | (s.mt[(k + 1) % 624] & 0x7fffffffu);
            s.mt[k] = s.mt[(k + 397) % 624] ^ (y >> 1) ^ ((y & 1u) ? 0x9908b0dfu : 0u);
        }
        s.mti = 0;
    }
    unsigned y = s.mt[s.mti++];
    y ^= y >> 11;
    y ^= (y << 7) & 0x9d2c5680u;
    y ^= (y << 15) & 0xefc60000u;
    y ^= y >> 18;
    return y;
}

static constexpr Tab make_tab() {
    MTState s{};
    s.mt[0] = 123u;
    for (int i = 1; i < 624; ++i)
        s.mt[i] = 1812433253u * (s.mt[i - 1] ^ (s.mt[i - 1] >> 30)) + (unsigned)i;
    s.mti = 624;
    int perm[256] = {};
    for (int i = 0; i < 256; ++i) perm[i] = i;
    for (int i = 255; i > 0; --i) {
        unsigned mask = (unsigned)i;
        mask |= mask >> 1; mask |= mask >> 2; mask |= mask >> 4;
        mask |= mask >> 8; mask |= mask >> 16;
        unsigned j = 0;
        do { j = mt_next(s) & mask; } while (j > (unsigned)i);
        int t = perm[i]; perm[i] = perm[j]; perm[j] = t;
    }
    bool g[256] = {};
    for (int k = 0; k < GHOSTN; ++k) g[perm[k]] = true;
    Tab t{};
    int rc = 0, gc = 0;
    for (int c = 0; c < 256; ++c) {
        if (g[c]) t.ghost[gc++] = c;
        else      t.rep[rc++] = c;
    }
    return t;
}

__constant__ Tab d_tab = make_tab();

// c1[d] = wb[d/3][d%3] (x1 filter, offsets d-7); c2[d] = wb[4-d/3][d%3]
// (x2 = group-reversed filter, same offsets). Verified mapping:
//   x1[l] = sum_d c1[d] x[l+d-7], group i = d/3 gated on 0 <= l-6+3i < LEN
//   x2[l] = sum_d c2[d] x[l+d-7], tap-d gate is the SAME (l-6+3*(d/3))
//   x3[l] = middle 3-tap (d = 6..8 of c1), ungated.
#define C1F(D) wb[(D) / 3][(D) % 3]
#define C2F(D) wb[4 - (D) / 3][(D) % 3]

// ===========================================================================
// Pass 1 (R12) — autocorrelation stats (R11 algebra, correctness-proven)
// with 8-FLOAT TRIPLE-ROLLING buffers in the main loop. R11 counters:
// VGPR=68 (4 over the 64 allocation boundary -> 4 waves/SIMD, Occupancy
// 30%, VALUBusy 22%, latency-bound). The 2x16-float double-buffer was the
// overshoot; 3x8-float rolling (24 regs, window Ba[8]+Bb[8]+Bc[0..5])
// puts the live set ~45-50 -> natural <=64 VGPR -> 8 waves/SIMD. No
// __launch_bounds__ forcing (R8 spill lesson).
//   blocks [0, 1584)      : 4 waves x 1 rep row each (stats only)
//   blocks [1584, 3440)   : ghost copy, one row per block
// ===========================================================================
__global__ __launch_bounds__(256) void pass1_kernel(const float* __restrict__ x,
                                                    const float* __restrict__ w1,
                                                    const float* __restrict__ w2,
                                                    float* __restrict__ stats_ws,
                                                    float* __restrict__ out) {
    const int blk = blockIdx.x;
    if (blk >= P1REPBLK) {
        // ghost pass-through: NT load (never re-read), plain store
        const int g = (blk - P1REPBLK) % GHOSTN;
        const int b = (blk - P1REPBLK) / GHOSTN;
        const int ch = d_tab.ghost[g];
        const f32x4* src = (const f32x4*)(x + ((size_t)b * CH + ch) * LEN);
        f32x4* dst = (f32x4*)(out + ((size_t)b * CH + REPN + g) * LEN);
#pragma unroll
        for (int k = 0; k < 4; ++k) {
            f32x4 t = __builtin_nontemporal_load(&src[threadIdx.x + 256 * k]);
            dst[threadIdx.x + 256 * k] = t;
        }
        return;
    }

    const int wv = (blk << 2) | (threadIdx.x >> 6);
    const int lane = threadIdx.x & 63;
    const int r = wv % REPN;
    const int b = wv / REPN;
    const float* row = x + ((size_t)b * CH + d_tab.rep[r]) * LEN;

    // ---- main accumulation: A[0..14], Sx over this lane's 64 elements ----
    float A[15];
#pragma unroll
    for (int dl = 0; dl < 15; ++dl) A[dl] = 0.f;
    float SX = 0.f;
    float Ba[8], Bb[8], Bc[8];
    const int base = lane << 6;

// 8-float chunk load (2x dwordx4); OOB chunks (lane 63 halo) -> zeros.
#define LOAD8(DST, OFF)                                                           \
    {                                                                             \
        if ((OFF) < LEN) {                                                        \
            const f32x4* q4_ = (const f32x4*)(row + (OFF));                       \
            f32x4 u0_ = q4_[0], u1_ = q4_[1];                                     \
            DST[0] = u0_.x; DST[1] = u0_.y; DST[2] = u0_.z; DST[3] = u0_.w;       \
            DST[4] = u1_.x; DST[5] = u1_.y; DST[6] = u1_.z; DST[7] = u1_.w;       \
        } else {                                                                  \
            _Pragma("unroll")                                                     \
            for (int t = 0; t < 8; ++t) DST[t] = 0.f;                             \
        }                                                                         \
    }

// A[dl] += x[u]x[u+dl] for u = P's 8 elements; window = P[8] ++ Q[8] ++ R[0..5]
#define ACC8(P, Q, R)                                                             \
    {                                                                             \
        _Pragma("unroll")                                                         \
        for (int j = 0; j < 8; ++j) {                                             \
            const float xj_ = P[j];                                               \
            SX += xj_;                                                            \
            _Pragma("unroll")                                                     \
            for (int dl = 0; dl < 15; ++dl) {                                     \
                const int t_ = j + dl;                                            \
                const float xd_ = (t_ < 8) ? P[t_]                                \
                                 : (t_ < 16) ? Q[t_ - 8] : R[t_ - 16];            \
                A[dl] = fmaf(xj_, xd_, A[dl]);                                    \
            }                                                                     \
        }                                                                         \
    }

    LOAD8(Ba, base);
    LOAD8(Bb, base + 8);
    LOAD8(Bc, base + 16);
    ACC8(Ba, Bb, Bc);                       // u in [base+ 0, base+ 8)
    LOAD8(Ba, base + 24);  ACC8(Bb, Bc, Ba); // u in [base+ 8, base+16)
    LOAD8(Bb, base + 32);  ACC8(Bc, Ba, Bb); // u in [base+16, base+24)
    LOAD8(Bc, base + 40);  ACC8(Ba, Bb, Bc); // u in [base+24, base+32)
    LOAD8(Ba, base + 48);  ACC8(Bb, Bc, Ba); // u in [base+32, base+40)
    LOAD8(Bb, base + 56);  ACC8(Bc, Ba, Bb); // u in [base+40, base+48)
    LOAD8(Bc, base + 64);  ACC8(Ba, Bb, Bc); // u in [base+48, base+56)
    LOAD8(Ba, base + 72);  ACC8(Bb, Bc, Ba); // u in [base+56, base+64)
#undef LOAD8
#undef ACC8

    // ---- weights (needed only from here on; keeps main-loop VGPR low) ----
    float wb[5][3];
    {
        const float* p1 = w1 + r * 15;
        const float* p2 = w2 + r * 15;
#pragma unroll
        for (int i = 0; i < 5; ++i)
#pragma unroll
            for (int t = 0; t < 3; ++t) wb[i][t] = p1[i * 3 + t] + p2[i * 3 + t];
    }

    // ---- boundary corrections: one output l per lane, lanes 0..25 ----
    // lanes 0..12  -> l = lane - 7      in [-7, 5]   (left)
    // lanes 13..25 -> l = 4090+lane-13  in [4090, 4102] (right)
    // out-of-range l: subtract ungated u1,u2,u3 (identity includes them);
    // in-range edge l: add (gated - ungated) for x1,x2 (x3 has no gating).
    float d1 = 0.f, d1q = 0.f, d2 = 0.f, d2q = 0.f, d3 = 0.f, d3q = 0.f;
    if (lane < 26) {
        const int l = (lane <= 12) ? (lane - 7) : (4090 + (lane - 13));
        float u1 = 0.f, u2 = 0.f, u3 = 0.f, g1 = 0.f, g2 = 0.f;
#pragma unroll
        for (int d = 0; d < 15; ++d) {
            const int p = l + d - 7;
            const float xd = ((unsigned)p < (unsigned)LEN) ? row[p] : 0.f;
            const float a1 = C1F(d) * xd;
            const float a2 = C2F(d) * xd;
            u1 += a1; u2 += a2;
            if (d >= 6 && d <= 8) u3 += a1;          // middle group = x3
            const bool gate = ((unsigned)(l - 6 + 3 * (d / 3)) < (unsigned)LEN);
            g1 += gate ? a1 : 0.f;
            g2 += gate ? a2 : 0.f;
        }
        if ((unsigned)l < (unsigned)LEN) {
            d1 = g1 - u1;  d1q = fmaf(g1, g1, -u1 * u1);
            d2 = g2 - u2;  d2q = fmaf(g2, g2, -u2 * u2);
            /* x3: gated == ungated in range -> no delta */
        } else {
            d1 = -u1;  d1q = -u1 * u1;
            d2 = -u2;  d2q = -u2 * u2;
            d3 = -u3;  d3q = -u3 * u3;
        }
    }

    // ---- wave reduce: A[15], SX, deltas[6] ----
#pragma unroll
    for (int off = 32; off > 0; off >>= 1) {
#pragma unroll
        for (int dl = 0; dl < 15; ++dl) A[dl] += __shfl_down(A[dl], off);
        SX += __shfl_down(SX, off);
        d1 += __shfl_down(d1, off);   d1q += __shfl_down(d1q, off);
        d2 += __shfl_down(d2, off);   d2q += __shfl_down(d2q, off);
        d3 += __shfl_down(d3, off);   d3q += __shfl_down(d3q, off);
    }

    if (lane == 0) {
        // rho-weighted autocorr sums (delta loop unrolled, wb refs static)
        float sq1 = 0.f, sq2 = 0.f;
#pragma unroll
        for (int dl = 0; dl < 15; ++dl) {
            float r1 = 0.f, r2 = 0.f;
#pragma unroll
            for (int d = 0; d + dl < 15; ++d) {
                r1 = fmaf(C1F(d), C1F(d + dl), r1);
                r2 = fmaf(C2F(d), C2F(d + dl), r2);
            }
            const float wA = (dl ? 2.f : 1.f) * A[dl];
            sq1 = fmaf(r1, wA, sq1);
            sq2 = fmaf(r2, wA, sq2);
        }
        const float c30 = wb[2][0], c31 = wb[2][1], c32 = wb[2][2];
        float sq3 = (c30 * c30 + c31 * c31 + c32 * c32) * A[0]
                  + 2.f * (c30 * c31 + c31 * c32) * A[1]
                  + 2.f * (c30 * c32) * A[2];
        float cs = 0.f;
#pragma unroll
        for (int i = 0; i < 5; ++i)
#pragma unroll
            for (int t = 0; t < 3; ++t) cs += wb[i][t];
        const float c3s = c30 + c31 + c32;

        stats_ws[(0 * REPN + r) * BATCH + b] = fmaf(cs, SX, d1);
        stats_ws[(1 * REPN + r) * BATCH + b] = sq1 + d1q;
        stats_ws[(2 * REPN + r) * BATCH + b] = fmaf(cs, SX, d2);   // sum(c2)==sum(c1)
        stats_ws[(3 * REPN + r) * BATCH + b] = sq2 + d2q;
        stats_ws[(4 * REPN + r) * BATCH + b] = fmaf(c3s, SX, d3);
        stats_ws[(5 * REPN + r) * BATCH + b] = sq3 + d3q;
    }
}

// ===========================================================================
// Pass 2 — barrier-free wave-per-row, rep rows ONLY (unchanged from R4/R6).
// ===========================================================================
__device__ __forceinline__ void load_fast(const float* __restrict__ row, int e, float* v) {
    const f32x4* q4 = (const f32x4*)(row + e - 8);
#pragma unroll
    for (int t = 0; t < 5; ++t) {
        f32x4 u = q4[t];
        v[4 * t] = u.x; v[4 * t + 1] = u.y; v[4 * t + 2] = u.z; v[4 * t + 3] = u.w;
    }
}

__device__ __forceinline__ void load_slow(const float* __restrict__ row, int e, float* v) {
#pragma unroll
    for (int d = 0; d < 20; ++d) {
        int fi = e - 8 + d;
        v[d] = ((unsigned)fi < (unsigned)LEN) ? row[fi] : 0.f;
    }
}

__global__ __launch_bounds__(256) void pass2_kernel(const float* __restrict__ x,
                                                    const float* __restrict__ w1,
                                                    const float* __restrict__ w2,
                                                    const float* __restrict__ stats_ws,
                                                    const float* __restrict__ g1, const float* __restrict__ b1,
                                                    const float* __restrict__ g2, const float* __restrict__ b2,
                                                    const float* __restrict__ g3, const float* __restrict__ b3,
                                                    float* __restrict__ out) {
    const int wv = (blockIdx.x << 2) | (threadIdx.x >> 6);
    const int lane = threadIdx.x & 63;
    const int r = wv % REPN;
    const int b = wv / REPN;
    const int ch = d_tab.rep[r];
    const float* row = x + ((size_t)b * CH + ch) * LEN;

    // BN finalize: lanes load the 32 batch partials (dup across halves), butterfly.
    float p[6];
    const int bb = lane & 31;
#pragma unroll
    for (int q = 0; q < 6; ++q) p[q] = stats_ws[(q * REPN + r) * BATCH + bb];
#pragma unroll
    for (int m = 1; m < 32; m <<= 1)
#pragma unroll
        for (int q = 0; q < 6; ++q) p[q] += __shfl_xor(p[q], m);

    const double invN = 1.0 / (double)(BATCH * LEN);
    float sc[3], sh[3];
    {
        const float gr[3] = {g1[r], g2[r], g3[r]};
        const float br[3] = {b1[r], b2[r], b3[r]};
#pragma unroll
        for (int q = 0; q < 3; ++q) {
            double mean = (double)p[2 * q] * invN;
            double var = (double)p[2 * q + 1] * invN - mean * mean;
            double inv = 1.0 / sqrt(var + 1e-5);
            double scale = (double)gr[q] * inv;
            sc[q] = (float)scale;
            sh[q] = (float)((double)br[q] - mean * scale);
        }
    }
    const float base = sh[0] + sh[1] + sh[2];

    float wb[5][3];
    const float* p1 = w1 + r * 15;
    const float* p2 = w2 + r * 15;
#pragma unroll
    for (int i = 0; i < 5; ++i)
#pragma unroll
        for (int t = 0; t < 3; ++t) wb[i][t] = p1[i * 3 + t] + p2[i * 3 + t];

    // Combined 15-tap filter (interior): tap d=3k+t applies to v[j+1+d].
    float c[15];
#pragma unroll
    for (int k = 0; k < 5; ++k)
#pragma unroll
        for (int t = 0; t < 3; ++t)
            c[3 * k + t] = fmaf(sc[0], wb[k][t], sc[1] * wb[4 - k][t]);
#pragma unroll
    for (int t = 0; t < 3; ++t) c[6 + t] = fmaf(sc[2], wb[2][t], c[6 + t]);

    float* orow = out + ((size_t)b * CH + r) * LEN;
    float v[20];

#define INTERIOR_QUAD(E)                                                          \
    {                                                                             \
        float o[4];                                                               \
        _Pragma("unroll")                                                         \
        for (int j = 0; j < 4; ++j) {                                             \
            float acc = base + v[j + 8];                                          \
            _Pragma("unroll")                                                     \
            for (int d = 0; d < 15; ++d) acc = fmaf(c[d], v[j + 1 + d], acc);     \
            o[j] = acc;                                                           \
        }                                                                         \
        f32x4 t = {o[0], o[1], o[2], o[3]};                                       \
        *(f32x4*)(orow + (E)) = t;                                                \
    }

#define EDGE_QUAD(E)                                                              \
    {                                                                             \
        float o[4];                                                               \
        _Pragma("unroll")                                                         \
        for (int j = 0; j < 4; ++j) {                                             \
            const int l = (E) + j;                                                \
            float x1 = 0.f, x2 = 0.f, x3 = 0.f;                                   \
            _Pragma("unroll")                                                     \
            for (int i = 0; i < 5; ++i) {                                         \
                float a1 = fmaf(wb[i][0], v[j + 1 + 3 * i],                       \
                           fmaf(wb[i][1], v[j + 2 + 3 * i],                       \
                                wb[i][2] * v[j + 3 + 3 * i]));                    \
                float a2 = fmaf(wb[i][0], v[j + 13 - 3 * i],                      \
                           fmaf(wb[i][1], v[j + 14 - 3 * i],                      \
                                wb[i][2] * v[j + 15 - 3 * i]));                   \
                if (i == 2) x3 = a1;                                              \
                a1 = ((unsigned)(l - 6 + 3 * i) < (unsigned)LEN) ? a1 : 0.f;      \
                a2 = ((unsigned)(l + 6 - 3 * i) < (unsigned)LEN) ? a2 : 0.f;      \
                x1 += a1; x2 += a2;                                               \
            }                                                                     \
            o[j] = fmaf(sc[0], x1, fmaf(sc[1], x2, fmaf(sc[2], x3, base + v[j + 8]))); \
        }                                                                         \
        f32x4 t = {o[0], o[1], o[2], o[3]};                                       \
        *(f32x4*)(orow + (E)) = t;                                                \
    }

    { // k = 0
        const int e = 4 * lane;
        if (lane < 2) { load_slow(row, e, v); EDGE_QUAD(e); }
        else          { load_fast(row, e, v); INTERIOR_QUAD(e); }
    }
#pragma unroll
    for (int k = 1; k < 15; ++k) {
        const int e = 4 * lane + 256 * k;
        load_fast(row, e, v);
        INTERIOR_QUAD(e);
    }
    { // k = 15
        const int e = 4 * lane + 3840;
        if (lane >= 62) { load_slow(row, e, v); EDGE_QUAD(e); }
        else            { load_fast(row, e, v); INTERIOR_QUAD(e); }
    }
#undef INTERIOR_QUAD
#undef EDGE_QUAD
}

extern "C" void kernel_launch(void* const* d_in, const int* in_sizes, int n_in,
                              void* d_out, int out_size, void* d_ws, size_t ws_size,
                              hipStream_t stream) {
    const float* x  = (const float*)d_in[0];
    const float* w1 = (const float*)d_in[1];
    const float* w2 = (const float*)d_in[2];
    const float* g1 = (const float*)d_in[3];
    const float* b1 = (const float*)d_in[4];
    const float* g2 = (const float*)d_in[5];
    const float* b2 = (const float*)d_in[6];
    const float* g3 = (const float*)d_in[7];
    const float* b3 = (const float*)d_in[8];
    float* out = (float*)d_out;
    float* stats_ws = (float*)d_ws;   // 6*198*32 floats = 152 KB

    // pass1: 1584 rep-stats blocks (autocorr, 8-float rolling buffers)
    //        + 1856 ghost copy blocks.
    pass1_kernel<<<P1REPBLK + NGHOST, 256, 0, stream>>>(x, w1, w2, stats_ws, out);
    // pass2: 6336 rep waves = 1584 blocks (barrier-free, plain stores).
    pass2_kernel<<<1584, 256, 0, stream>>>(x, w1, w2, stats_ws,
                                           g1, b1, g2, b2, g3, b3, out);
}

// Round 13
// 84.010 us; speedup vs baseline: 1.2180x; 1.0173x over previous
//
#include <hip/hip_runtime.h>

#define LEN 4096
#define BATCH 32
#define CH 256
#define REPN 198
#define GHOSTN 58
#define NROW (REPN * BATCH)     /* 6336 */
#define NGHOST (GHOSTN * BATCH) /* 1856 */
#define P1REPBLK 1584           /* 6336 rep waves / 4 waves per block */

typedef float f32x4 __attribute__((ext_vector_type(4)));

// ---------------------------------------------------------------------------
// COMPILE-TIME numpy-legacy RNG replication (verified rounds 1-8):
// np.random.seed(123); np.random.choice(256, 58, replace=False)
// ---------------------------------------------------------------------------
struct MTState { unsigned mt[624]; int mti; };
struct Tab { int rep[REPN]; int ghost[GHOSTN]; };

static constexpr unsigned mt_next(MTState& s) {
    if (s.mti >= 624) {
        for (int k = 0; k < 624; ++k) {
            unsigned y = (s.mt[k] & 0x80000000u) | (s.mt[(k + 1) % 624] & 0x7fffffffu);
            s.mt[k] = s.mt[(k + 397) % 624] ^ (y >> 1) ^ ((y & 1u) ? 0x9908b0dfu : 0u);
        }
        s.mti = 0;
    }
    unsigned y = s.mt[s.mti++];
    y ^= y >> 11;
    y ^= (y << 7) & 0x9d2c5680u;
    y ^= (y << 15) & 0xefc60000u;
    y ^= y >> 18;
    return y;
}

static constexpr Tab make_tab() {
    MTState s{};
    s.mt[0] = 123u;
    for (int i = 1; i < 624; ++i)
        s.mt[i] = 1812433253u * (s.mt[i - 1] ^ (s.mt[i - 1] >> 30)) + (unsigned)i;
    s.mti = 624;
    int perm[256] = {};
    for (int i = 0; i < 256; ++i) perm[i] = i;
    for (int i = 255; i > 0; --i) {
        unsigned mask = (unsigned)i;
        mask |= mask >> 1; mask |= mask >> 2; mask |= mask >> 4;
        mask |= mask >> 8; mask |= mask >> 16;
        unsigned j = 0;
        do { j = mt_next(s) & mask; } while (j > (unsigned)i);
        int t = perm[i]; perm[i] = perm[j]; perm[j] = t;
    }
    bool g[256] = {};
    for (int k = 0; k < GHOSTN; ++k) g[perm[k]] = true;
    Tab t{};
    int rc = 0, gc = 0;
    for (int c = 0; c < 256; ++c) {
        if (g[c]) t.ghost[gc++] = c;
        else      t.rep[rc++] = c;
    }
    return t;
}

__constant__ Tab d_tab = make_tab();

// c1[d] = wb[d/3][d%3] (x1 filter, offsets d-7); c2[d] = wb[4-d/3][d%3]
// (x2 = group-reversed filter, same offsets). Verified mapping:
//   x1[l] = sum_d c1[d] x[l+d-7], group i = d/3 gated on 0 <= l-6+3i < LEN
//   x2[l] = sum_d c2[d] x[l+d-7], tap-d gate is the SAME (l-6+3*(d/3))
//   x3[l] = middle 3-tap (d = 6..8 of c1), ungated.
#define C1F(D) wb[(D) / 3][(D) % 3]
#define C2F(D) wb[4 - (D) / 3][(D) % 3]

// ===========================================================================
// Pass 1 (R13) — autocorrelation stats (R11/R12 algebra, correctness-proven)
// with 5-BUFFER ROLLING PREFETCH. R12 showed VGPR=68 is in the 128-register
// allocation granule -> ~60 regs of FREE headroom (occupancy unchanged).
// Spend it on prefetch depth: loads stay 2-3 chunks (~512-768 cover cycles)
// ahead of each ACC8 instead of 1. Chunk ck lives in buffer B[k mod 5].
//   blocks [0, 1584)      : 4 waves x 1 rep row each (stats only)
//   blocks [1584, 3440)   : ghost copy, one row per block
// ===========================================================================
__global__ __launch_bounds__(256) void pass1_kernel(const float* __restrict__ x,
                                                    const float* __restrict__ w1,
                                                    const float* __restrict__ w2,
                                                    float* __restrict__ stats_ws,
                                                    float* __restrict__ out) {
    const int blk = blockIdx.x;
    if (blk >= P1REPBLK) {
        // ghost pass-through: NT load (never re-read), plain store
        const int g = (blk - P1REPBLK) % GHOSTN;
        const int b = (blk - P1REPBLK) / GHOSTN;
        const int ch = d_tab.ghost[g];
        const f32x4* src = (const f32x4*)(x + ((size_t)b * CH + ch) * LEN);
        f32x4* dst = (f32x4*)(out + ((size_t)b * CH + REPN + g) * LEN);
#pragma unroll
        for (int k = 0; k < 4; ++k) {
            f32x4 t = __builtin_nontemporal_load(&src[threadIdx.x + 256 * k]);
            dst[threadIdx.x + 256 * k] = t;
        }
        return;
    }

    const int wv = (blk << 2) | (threadIdx.x >> 6);
    const int lane = threadIdx.x & 63;
    const int r = wv % REPN;
    const int b = wv / REPN;
    const float* row = x + ((size_t)b * CH + d_tab.rep[r]) * LEN;

    // ---- main accumulation: A[0..14], Sx over this lane's 64 elements ----
    float A[15];
#pragma unroll
    for (int dl = 0; dl < 15; ++dl) A[dl] = 0.f;
    float SX = 0.f;
    float B0[8], B1[8], B2[8], B3[8], B4[8];
    const int base = lane << 6;

// 8-float chunk load (2x dwordx4); OOB chunks (lane 63 halo) -> zeros.
#define LOAD8(DST, OFF)                                                           \
    {                                                                             \
        if ((OFF) < LEN) {                                                        \
            const f32x4* q4_ = (const f32x4*)(row + (OFF));                       \
            f32x4 u0_ = q4_[0], u1_ = q4_[1];                                     \
            DST[0] = u0_.x; DST[1] = u0_.y; DST[2] = u0_.z; DST[3] = u0_.w;       \
            DST[4] = u1_.x; DST[5] = u1_.y; DST[6] = u1_.z; DST[7] = u1_.w;       \
        } else {                                                                  \
            _Pragma("unroll")                                                     \
            for (int t = 0; t < 8; ++t) DST[t] = 0.f;                             \
        }                                                                         \
    }

// A[dl] += x[u]x[u+dl] for u = P's 8 elements; window = P[8] ++ Q[8] ++ R[0..5]
#define ACC8(P, Q, R)                                                             \
    {                                                                             \
        _Pragma("unroll")                                                         \
        for (int j = 0; j < 8; ++j) {                                             \
            const float xj_ = P[j];                                               \
            SX += xj_;                                                            \
            _Pragma("unroll")                                                     \
            for (int dl = 0; dl < 15; ++dl) {                                     \
                const int t_ = j + dl;                                            \
                const float xd_ = (t_ < 8) ? P[t_]                                \
                                 : (t_ < 16) ? Q[t_ - 8] : R[t_ - 16];            \
                A[dl] = fmaf(xj_, xd_, A[dl]);                                    \
            }                                                                     \
        }                                                                         \
    }

    // Deep-prefetch rolling schedule: buf(ck) = k mod 5; at ACC8(ck) chunks
    // ck+3, ck+4 are already in flight.
    LOAD8(B0, base);
    LOAD8(B1, base + 8);
    LOAD8(B2, base + 16);
    LOAD8(B3, base + 24);
    LOAD8(B4, base + 32);
    ACC8(B0, B1, B2);  LOAD8(B0, base + 40);   // c0 ; issue c5
    ACC8(B1, B2, B3);  LOAD8(B1, base + 48);   // c1 ; issue c6
    ACC8(B2, B3, B4);  LOAD8(B2, base + 56);   // c2 ; issue c7
    ACC8(B3, B4, B0);  LOAD8(B3, base + 64);   // c3 ; issue c8
    ACC8(B4, B0, B1);  LOAD8(B4, base + 72);   // c4 ; issue c9
    ACC8(B0, B1, B2);                           // c5
    ACC8(B1, B2, B3);                           // c6
    ACC8(B2, B3, B4);                           // c7
#undef LOAD8
#undef ACC8

    // ---- weights (needed only from here on; keeps main-loop VGPR low) ----
    float wb[5][3];
    {
        const float* p1 = w1 + r * 15;
        const float* p2 = w2 + r * 15;
#pragma unroll
        for (int i = 0; i < 5; ++i)
#pragma unroll
            for (int t = 0; t < 3; ++t) wb[i][t] = p1[i * 3 + t] + p2[i * 3 + t];
    }

    // ---- boundary corrections: one output l per lane, lanes 0..25 ----
    // lanes 0..12  -> l = lane - 7      in [-7, 5]   (left)
    // lanes 13..25 -> l = 4090+lane-13  in [4090, 4102] (right)
    // out-of-range l: subtract ungated u1,u2,u3 (identity includes them);
    // in-range edge l: add (gated - ungated) for x1,x2 (x3 has no gating).
    float d1 = 0.f, d1q = 0.f, d2 = 0.f, d2q = 0.f, d3 = 0.f, d3q = 0.f;
    if (lane < 26) {
        const int l = (lane <= 12) ? (lane - 7) : (4090 + (lane - 13));
        float u1 = 0.f, u2 = 0.f, u3 = 0.f, g1 = 0.f, g2 = 0.f;
#pragma unroll
        for (int d = 0; d < 15; ++d) {
            const int p = l + d - 7;
            const float xd = ((unsigned)p < (unsigned)LEN) ? row[p] : 0.f;
            const float a1 = C1F(d) * xd;
            const float a2 = C2F(d) * xd;
            u1 += a1; u2 += a2;
            if (d >= 6 && d <= 8) u3 += a1;          // middle group = x3
            const bool gate = ((unsigned)(l - 6 + 3 * (d / 3)) < (unsigned)LEN);
            g1 += gate ? a1 : 0.f;
            g2 += gate ? a2 : 0.f;
        }
        if ((unsigned)l < (unsigned)LEN) {
            d1 = g1 - u1;  d1q = fmaf(g1, g1, -u1 * u1);
            d2 = g2 - u2;  d2q = fmaf(g2, g2, -u2 * u2);
            /* x3: gated == ungated in range -> no delta */
        } else {
            d1 = -u1;  d1q = -u1 * u1;
            d2 = -u2;  d2q = -u2 * u2;
            d3 = -u3;  d3q = -u3 * u3;
        }
    }

    // ---- wave reduce: A[15], SX, deltas[6] ----
#pragma unroll
    for (int off = 32; off > 0; off >>= 1) {
#pragma unroll
        for (int dl = 0; dl < 15; ++dl) A[dl] += __shfl_down(A[dl], off);
        SX += __shfl_down(SX, off);
        d1 += __shfl_down(d1, off);   d1q += __shfl_down(d1q, off);
        d2 += __shfl_down(d2, off);   d2q += __shfl_down(d2q, off);
        d3 += __shfl_down(d3, off);   d3q += __shfl_down(d3q, off);
    }

    if (lane == 0) {
        // rho-weighted autocorr sums (delta loop unrolled, wb refs static)
        float sq1 = 0.f, sq2 = 0.f;
#pragma unroll
        for (int dl = 0; dl < 15; ++dl) {
            float r1 = 0.f, r2 = 0.f;
#pragma unroll
            for (int d = 0; d + dl < 15; ++d) {
                r1 = fmaf(C1F(d), C1F(d + dl), r1);
                r2 = fmaf(C2F(d), C2F(d + dl), r2);
            }
            const float wA = (dl ? 2.f : 1.f) * A[dl];
            sq1 = fmaf(r1, wA, sq1);
            sq2 = fmaf(r2, wA, sq2);
        }
        const float c30 = wb[2][0], c31 = wb[2][1], c32 = wb[2][2];
        float sq3 = (c30 * c30 + c31 * c31 + c32 * c32) * A[0]
                  + 2.f * (c30 * c31 + c31 * c32) * A[1]
                  + 2.f * (c30 * c32) * A[2];
        float cs = 0.f;
#pragma unroll
        for (int i = 0; i < 5; ++i)
#pragma unroll
            for (int t = 0; t < 3; ++t) cs += wb[i][t];
        const float c3s = c30 + c31 + c32;

        stats_ws[(0 * REPN + r) * BATCH + b] = fmaf(cs, SX, d1);
        stats_ws[(1 * REPN + r) * BATCH + b] = sq1 + d1q;
        stats_ws[(2 * REPN + r) * BATCH + b] = fmaf(cs, SX, d2);   // sum(c2)==sum(c1)
        stats_ws[(3 * REPN + r) * BATCH + b] = sq2 + d2q;
        stats_ws[(4 * REPN + r) * BATCH + b] = fmaf(c3s, SX, d3);
        stats_ws[(5 * REPN + r) * BATCH + b] = sq3 + d3q;
    }
}

// ===========================================================================
// Pass 2 (R13) — barrier-free wave-per-row with TWO-WINDOW SOFTWARE PIPELINE
// over the 14 interior rounds (prefetch k+1/k+2 while computing k). Edge
// rounds (k=0, k=15) verbatim. +20 regs live — free inside the 128-granule.
// ===========================================================================
__device__ __forceinline__ void load_fast(const float* __restrict__ row, int e, float* v) {
    const f32x4* q4 = (const f32x4*)(row + e - 8);
#pragma unroll
    for (int t = 0; t < 5; ++t) {
        f32x4 u = q4[t];
        v[4 * t] = u.x; v[4 * t + 1] = u.y; v[4 * t + 2] = u.z; v[4 * t + 3] = u.w;
    }
}

__device__ __forceinline__ void load_slow(const float* __restrict__ row, int e, float* v) {
#pragma unroll
    for (int d = 0; d < 20; ++d) {
        int fi = e - 8 + d;
        v[d] = ((unsigned)fi < (unsigned)LEN) ? row[fi] : 0.f;
    }
}

__global__ __launch_bounds__(256) void pass2_kernel(const float* __restrict__ x,
                                                    const float* __restrict__ w1,
                                                    const float* __restrict__ w2,
                                                    const float* __restrict__ stats_ws,
                                                    const float* __restrict__ g1, const float* __restrict__ b1,
                                                    const float* __restrict__ g2, const float* __restrict__ b2,
                                                    const float* __restrict__ g3, const float* __restrict__ b3,
                                                    float* __restrict__ out) {
    const int wv = (blockIdx.x << 2) | (threadIdx.x >> 6);
    const int lane = threadIdx.x & 63;
    const int r = wv % REPN;
    const int b = wv / REPN;
    const int ch = d_tab.rep[r];
    const float* row = x + ((size_t)b * CH + ch) * LEN;

    // BN finalize: lanes load the 32 batch partials (dup across halves), butterfly.
    float p[6];
    const int bb = lane & 31;
#pragma unroll
    for (int q = 0; q < 6; ++q) p[q] = stats_ws[(q * REPN + r) * BATCH + bb];
#pragma unroll
    for (int m = 1; m < 32; m <<= 1)
#pragma unroll
        for (int q = 0; q < 6; ++q) p[q] += __shfl_xor(p[q], m);

    const double invN = 1.0 / (double)(BATCH * LEN);
    float sc[3], sh[3];
    {
        const float gr[3] = {g1[r], g2[r], g3[r]};
        const float br[3] = {b1[r], b2[r], b3[r]};
#pragma unroll
        for (int q = 0; q < 3; ++q) {
            double mean = (double)p[2 * q] * invN;
            double var = (double)p[2 * q + 1] * invN - mean * mean;
            double inv = 1.0 / sqrt(var + 1e-5);
            double scale = (double)gr[q] * inv;
            sc[q] = (float)scale;
            sh[q] = (float)((double)br[q] - mean * scale);
        }
    }
    const float base = sh[0] + sh[1] + sh[2];

    float wb[5][3];
    const float* p1 = w1 + r * 15;
    const float* p2 = w2 + r * 15;
#pragma unroll
    for (int i = 0; i < 5; ++i)
#pragma unroll
        for (int t = 0; t < 3; ++t) wb[i][t] = p1[i * 3 + t] + p2[i * 3 + t];

    // Combined 15-tap filter (interior): tap d=3k+t applies to v[j+1+d].
    float c[15];
#pragma unroll
    for (int k = 0; k < 5; ++k)
#pragma unroll
        for (int t = 0; t < 3; ++t)
            c[3 * k + t] = fmaf(sc[0], wb[k][t], sc[1] * wb[4 - k][t]);
#pragma unroll
    for (int t = 0; t < 3; ++t) c[6 + t] = fmaf(sc[2], wb[2][t], c[6 + t]);

    float* orow = out + ((size_t)b * CH + r) * LEN;
    float vA[20], vB[20];

#define INTERIOR_QUAD(E, V)                                                       \
    {                                                                             \
        float o[4];                                                               \
        _Pragma("unroll")                                                         \
        for (int j = 0; j < 4; ++j) {                                             \
            float acc = base + V[j + 8];                                          \
            _Pragma("unroll")                                                     \
            for (int d = 0; d < 15; ++d) acc = fmaf(c[d], V[j + 1 + d], acc);     \
            o[j] = acc;                                                           \
        }                                                                         \
        f32x4 t = {o[0], o[1], o[2], o[3]};                                       \
        *(f32x4*)(orow + (E)) = t;                                                \
    }

#define EDGE_QUAD(E, V)                                                           \
    {                                                                             \
        float o[4];                                                               \
        _Pragma("unroll")                                                         \
        for (int j = 0; j < 4; ++j) {                                             \
            const int l = (E) + j;                                                \
            float x1 = 0.f, x2 = 0.f, x3 = 0.f;                                   \
            _Pragma("unroll")                                                     \
            for (int i = 0; i < 5; ++i) {                                         \
                float a1 = fmaf(wb[i][0], V[j + 1 + 3 * i],                       \
                           fmaf(wb[i][1], V[j + 2 + 3 * i],                       \
                                wb[i][2] * V[j + 3 + 3 * i]));                    \
                float a2 = fmaf(wb[i][0], V[j + 13 - 3 * i],                      \
                           fmaf(wb[i][1], V[j + 14 - 3 * i],                      \
                                wb[i][2] * V[j + 15 - 3 * i]));                   \
                if (i == 2) x3 = a1;                                              \
                a1 = ((unsigned)(l - 6 + 3 * i) < (unsigned)LEN) ? a1 : 0.f;      \
                a2 = ((unsigned)(l + 6 - 3 * i) < (unsigned)LEN) ? a2 : 0.f;      \
                x1 += a1; x2 += a2;                                               \
            }                                                                     \
            o[j] = fmaf(sc[0], x1, fmaf(sc[1], x2, fmaf(sc[2], x3, base + V[j + 8]))); \
        }                                                                         \
        f32x4 t = {o[0], o[1], o[2], o[3]};                                       \
        *(f32x4*)(orow + (E)) = t;                                                \
    }

    { // k = 0 (edge lanes 0,1)
        const int e = 4 * lane;
        if (lane < 2) { load_slow(row, e, vA); EDGE_QUAD(e, vA); }
        else          { load_fast(row, e, vA); INTERIOR_QUAD(e, vA); }
    }
    // interior k = 1..14, two-window pipeline (7 pairs)
    load_fast(row, 4 * lane + 256, vA);           // prefetch k=1
#pragma unroll
    for (int kk = 0; kk < 7; ++kk) {
        const int k = 1 + 2 * kk;
        const int eA = 4 * lane + 256 * k;
        const int eB = eA + 256;
        load_fast(row, eB, vB);                   // prefetch k+1
        INTERIOR_QUAD(eA, vA);                    // compute k
        if (kk < 6) load_fast(row, eB + 256, vA); // prefetch k+2
        INTERIOR_QUAD(eB, vB);                    // compute k+1
    }
    { // k = 15 (edge lanes 62,63)
        const int e = 4 * lane + 3840;
        if (lane >= 62) { load_slow(row, e, vA); EDGE_QUAD(e, vA); }
        else            { load_fast(row, e, vA); INTERIOR_QUAD(e, vA); }
    }
#undef INTERIOR_QUAD
#undef EDGE_QUAD
}

extern "C" void kernel_launch(void* const* d_in, const int* in_sizes, int n_in,
                              void* d_out, int out_size, void* d_ws, size_t ws_size,
                              hipStream_t stream) {
    const float* x  = (const float*)d_in[0];
    const float* w1 = (const float*)d_in[1];
    const float* w2 = (const float*)d_in[2];
    const float* g1 = (const float*)d_in[3];
    const float* b1 = (const float*)d_in[4];
    const float* g2 = (const float*)d_in[5];
    const float* b2 = (const float*)d_in[6];
    const float* g3 = (const float*)d_in[7];
    const float* b3 = (const float*)d_in[8];
    float* out = (float*)d_out;
    float* stats_ws = (float*)d_ws;   // 6*198*32 floats = 152 KB

    // pass1: 1584 rep-stats blocks (autocorr, 5-buffer rolling prefetch)
    //        + 1856 ghost copy blocks.
    pass1_kernel<<<P1REPBLK + NGHOST, 256, 0, stream>>>(x, w1, w2, stats_ws, out);
    // pass2: 6336 rep waves = 1584 blocks (two-window pipelined).
    pass2_kernel<<<1584, 256, 0, stream>>>(x, w1, w2, stats_ws,
                                           g1, b1, g2, b2, g3, b3, out);
}

// Round 14
// 78.527 us; speedup vs baseline: 1.3030x; 1.0698x over previous
//
#include <hip/hip_runtime.h>

#define LEN 4096
#define BATCH 32
#define CH 256
#define REPN 198
#define GHOSTN 58
#define NROW (REPN * BATCH)     /* 6336 */
#define NGHOST (GHOSTN * BATCH) /* 1856 */
#define P1REPBLK 3168           /* 6336 rows x 2 halves / 4 waves */
#define P2REPBLK 3168           /* 12672 half-row waves / 4 */

typedef float f32x4 __attribute__((ext_vector_type(4)));

// ---------------------------------------------------------------------------
// COMPILE-TIME numpy-legacy RNG replication (verified rounds 1-8):
// np.random.seed(123); np.random.choice(256, 58, replace=False)
// ---------------------------------------------------------------------------
struct MTState { unsigned mt[624]; int mti; };
struct Tab { int rep[REPN]; int ghost[GHOSTN]; };

static constexpr unsigned mt_next(MTState& s) {
    if (s.mti >= 624) {
        for (int k = 0; k < 624; ++k) {
            unsigned y = (s.mt[k] & 0x80000000u) | (s.mt[(k + 1) % 624] & 0x7fffffffu);
            s.mt[k] = s.mt[(k + 397) % 624] ^ (y >> 1) ^ ((y & 1u) ? 0x9908b0dfu : 0u);
        }
        s.mti = 0;
    }
    unsigned y = s.mt[s.mti++];
    y ^= y >> 11;
    y ^= (y << 7) & 0x9d2c5680u;
    y ^= (y << 15) & 0xefc60000u;
    y ^= y >> 18;
    return y;
}

static constexpr Tab make_tab() {
    MTState s{};
    s.mt[0] = 123u;
    for (int i = 1; i < 624; ++i)
        s.mt[i] = 1812433253u * (s.mt[i - 1] ^ (s.mt[i - 1] >> 30)) + (unsigned)i;
    s.mti = 624;
    int perm[256] = {};
    for (int i = 0; i < 256; ++i) perm[i] = i;
    for (int i = 255; i > 0; --i) {
        unsigned mask = (unsigned)i;
        mask |= mask >> 1; mask |= mask >> 2; mask |= mask >> 4;
        mask |= mask >> 8; mask |= mask >> 16;
        unsigned j = 0;
        do { j = mt_next(s) & mask; } while (j > (unsigned)i);
        int t = perm[i]; perm[i] = perm[j]; perm[j] = t;
    }
    bool g[256] = {};
    for (int k = 0; k < GHOSTN; ++k) g[perm[k]] = true;
    Tab t{};
    int rc = 0, gc = 0;
    for (int c = 0; c < 256; ++c) {
        if (g[c]) t.ghost[gc++] = c;
        else      t.rep[rc++] = c;
    }
    return t;
}

__constant__ Tab d_tab = make_tab();

// c1[d] = wb[d/3][d%3] (x1 filter, offsets d-7); c2[d] = wb[4-d/3][d%3]
// (x2 = group-reversed filter, same offsets). Verified mapping:
//   x1[l] = sum_d c1[d] x[l+d-7], group i = d/3 gated on 0 <= l-6+3i < LEN
//   x2[l] = sum_d c2[d] x[l+d-7], tap-d gate is the SAME (l-6+3*(d/3))
//   x3[l] = middle 3-tap (d = 6..8 of c1), ungated.
#define C1F(D) wb[(D) / 3][(D) % 3]
#define C2F(D) wb[4 - (D) / 3][(D) % 3]

// ===========================================================================
// Pass 1 (R14) — autocorrelation stats (R11-R13 algebra, correctness-proven)
// at HALF-ROW PER WAVE. R13 counters: Occupancy 29.6% < the 50% cap allowed
// by 68 VGPR -> the binder is work granularity (long uneven blocks, 8-round
// dependent chains), not registers. Half-row: 2x waves, 1/2 duration, 32
// elems/lane, all 6 chunk loads prefetched up front, 4 ACC8. Halves combine
// via end-of-block LDS exchange (single barrier AFTER all mem/FMA work).
//   blocks [0, 3168)      : 4 waves = 2 rows x 2 halves (stats only)
//   blocks [3168, 5024)   : ghost copy, one row per block
// ===========================================================================
__global__ __launch_bounds__(256) void pass1_kernel(const float* __restrict__ x,
                                                    const float* __restrict__ w1,
                                                    const float* __restrict__ w2,
                                                    float* __restrict__ stats_ws,
                                                    float* __restrict__ out) {
    const int blk = blockIdx.x;
    if (blk >= P1REPBLK) {
        // ghost pass-through: NT load (never re-read), plain store
        const int g = (blk - P1REPBLK) % GHOSTN;
        const int b = (blk - P1REPBLK) / GHOSTN;
        const int ch = d_tab.ghost[g];
        const f32x4* src = (const f32x4*)(x + ((size_t)b * CH + ch) * LEN);
        f32x4* dst = (f32x4*)(out + ((size_t)b * CH + REPN + g) * LEN);
#pragma unroll
        for (int k = 0; k < 4; ++k) {
            f32x4 t = __builtin_nontemporal_load(&src[threadIdx.x + 256 * k]);
            dst[threadIdx.x + 256 * k] = t;
        }
        return;
    }

    __shared__ float comb[4][22];
    const int widx = threadIdx.x >> 6;
    const int lane = threadIdx.x & 63;
    const int rowid = (blk << 1) | (widx >> 1);
    const int half = widx & 1;
    const int r = rowid % REPN;
    const int b = rowid / REPN;
    const float* row = x + ((size_t)b * CH + d_tab.rep[r]) * LEN;

    // ---- main accumulation: A[0..14], Sx over this lane's 32 elements ----
    float A[15];
#pragma unroll
    for (int dl = 0; dl < 15; ++dl) A[dl] = 0.f;
    float SX = 0.f;
    float B0[8], B1[8], B2[8], B3[8], B4[8], B5[8];
    const int base = (half << 11) + (lane << 5);

// 8-float chunk load (2x dwordx4); chunks are 8-aligned so a chunk is either
// fully in-range or fully OOB (halo past row end) -> zeros.
#define LOAD8(DST, OFF)                                                           \
    {                                                                             \
        if ((OFF) < LEN) {                                                        \
            const f32x4* q4_ = (const f32x4*)(row + (OFF));                       \
            f32x4 u0_ = q4_[0], u1_ = q4_[1];                                     \
            DST[0] = u0_.x; DST[1] = u0_.y; DST[2] = u0_.z; DST[3] = u0_.w;       \
            DST[4] = u1_.x; DST[5] = u1_.y; DST[6] = u1_.z; DST[7] = u1_.w;       \
        } else {                                                                  \
            _Pragma("unroll")                                                     \
            for (int t = 0; t < 8; ++t) DST[t] = 0.f;                             \
        }                                                                         \
    }

// A[dl] += x[u]x[u+dl] for u = P's 8 elements; window = P[8] ++ Q[8] ++ R[0..5]
#define ACC8(P, Q, R)                                                             \
    {                                                                             \
        _Pragma("unroll")                                                         \
        for (int j = 0; j < 8; ++j) {                                             \
            const float xj_ = P[j];                                               \
            SX += xj_;                                                            \
            _Pragma("unroll")                                                     \
            for (int dl = 0; dl < 15; ++dl) {                                     \
                const int t_ = j + dl;                                            \
                const float xd_ = (t_ < 8) ? P[t_]                                \
                                 : (t_ < 16) ? Q[t_ - 8] : R[t_ - 16];            \
                A[dl] = fmaf(xj_, xd_, A[dl]);                                    \
            }                                                                     \
        }                                                                         \
    }

    // all 6 chunks issued up front (deep prefetch), then 4 ACC8
    LOAD8(B0, base);
    LOAD8(B1, base + 8);
    LOAD8(B2, base + 16);
    LOAD8(B3, base + 24);
    LOAD8(B4, base + 32);
    LOAD8(B5, base + 40);
    ACC8(B0, B1, B2);   // u in [base+ 0, base+ 8)
    ACC8(B1, B2, B3);   // u in [base+ 8, base+16)
    ACC8(B2, B3, B4);   // u in [base+16, base+24)
    ACC8(B3, B4, B5);   // u in [base+24, base+32)
#undef LOAD8
#undef ACC8

    // ---- weights (needed only from here on) ----
    float wb[5][3];
    {
        const float* p1 = w1 + r * 15;
        const float* p2 = w2 + r * 15;
#pragma unroll
        for (int i = 0; i < 5; ++i)
#pragma unroll
            for (int t = 0; t < 3; ++t) wb[i][t] = p1[i * 3 + t] + p2[i * 3 + t];
    }

    // ---- boundary corrections (half 0 wave only): one output l per lane ----
    // lanes 0..12  -> l = lane - 7      in [-7, 5]   (left)
    // lanes 13..25 -> l = 4090+lane-13  in [4090, 4102] (right)
    // out-of-range l: subtract ungated u1,u2,u3; in-range edge l: add
    // (gated - ungated) for x1,x2 (x3 has no gating). Verified R11-R13.
    float d1 = 0.f, d1q = 0.f, d2 = 0.f, d2q = 0.f, d3 = 0.f, d3q = 0.f;
    if (half == 0 && lane < 26) {
        const int l = (lane <= 12) ? (lane - 7) : (4090 + (lane - 13));
        float u1 = 0.f, u2 = 0.f, u3 = 0.f, g1 = 0.f, g2 = 0.f;
#pragma unroll
        for (int d = 0; d < 15; ++d) {
            const int p = l + d - 7;
            const float xd = ((unsigned)p < (unsigned)LEN) ? row[p] : 0.f;
            const float a1 = C1F(d) * xd;
            const float a2 = C2F(d) * xd;
            u1 += a1; u2 += a2;
            if (d >= 6 && d <= 8) u3 += a1;          // middle group = x3
            const bool gate = ((unsigned)(l - 6 + 3 * (d / 3)) < (unsigned)LEN);
            g1 += gate ? a1 : 0.f;
            g2 += gate ? a2 : 0.f;
        }
        if ((unsigned)l < (unsigned)LEN) {
            d1 = g1 - u1;  d1q = fmaf(g1, g1, -u1 * u1);
            d2 = g2 - u2;  d2q = fmaf(g2, g2, -u2 * u2);
            /* x3: gated == ungated in range -> no delta */
        } else {
            d1 = -u1;  d1q = -u1 * u1;
            d2 = -u2;  d2q = -u2 * u2;
            d3 = -u3;  d3q = -u3 * u3;
        }
    }

    // ---- wave reduce: A[15], SX, deltas[6] ----
#pragma unroll
    for (int off = 32; off > 0; off >>= 1) {
#pragma unroll
        for (int dl = 0; dl < 15; ++dl) A[dl] += __shfl_down(A[dl], off);
        SX += __shfl_down(SX, off);
        d1 += __shfl_down(d1, off);   d1q += __shfl_down(d1q, off);
        d2 += __shfl_down(d2, off);   d2q += __shfl_down(d2q, off);
        d3 += __shfl_down(d3, off);   d3q += __shfl_down(d3q, off);
    }

    // ---- combine halves via LDS (single barrier, after all mem/FMA) ----
    if (lane == 0) {
#pragma unroll
        for (int dl = 0; dl < 15; ++dl) comb[widx][dl] = A[dl];
        comb[widx][15] = SX;
        comb[widx][16] = d1;  comb[widx][17] = d1q;
        comb[widx][18] = d2;  comb[widx][19] = d2q;
        comb[widx][20] = d3;  comb[widx][21] = d3q;
    }
    __syncthreads();

    if (half == 0 && lane == 0) {
        float Af[15];
#pragma unroll
        for (int dl = 0; dl < 15; ++dl) Af[dl] = comb[widx][dl] + comb[widx + 1][dl];
        const float SXf = comb[widx][15] + comb[widx + 1][15];
        const float e1  = comb[widx][16] + comb[widx + 1][16];
        const float e1q = comb[widx][17] + comb[widx + 1][17];
        const float e2  = comb[widx][18] + comb[widx + 1][18];
        const float e2q = comb[widx][19] + comb[widx + 1][19];
        const float e3  = comb[widx][20] + comb[widx + 1][20];
        const float e3q = comb[widx][21] + comb[widx + 1][21];

        // rho-weighted autocorr sums (verified finalize, R11-R13)
        float sq1 = 0.f, sq2 = 0.f;
#pragma unroll
        for (int dl = 0; dl < 15; ++dl) {
            float r1 = 0.f, r2 = 0.f;
#pragma unroll
            for (int d = 0; d + dl < 15; ++d) {
                r1 = fmaf(C1F(d), C1F(d + dl), r1);
                r2 = fmaf(C2F(d), C2F(d + dl), r2);
            }
            const float wA = (dl ? 2.f : 1.f) * Af[dl];
            sq1 = fmaf(r1, wA, sq1);
            sq2 = fmaf(r2, wA, sq2);
        }
        const float c30 = wb[2][0], c31 = wb[2][1], c32 = wb[2][2];
        float sq3 = (c30 * c30 + c31 * c31 + c32 * c32) * Af[0]
                  + 2.f * (c30 * c31 + c31 * c32) * Af[1]
                  + 2.f * (c30 * c32) * Af[2];
        float cs = 0.f;
#pragma unroll
        for (int i = 0; i < 5; ++i)
#pragma unroll
            for (int t = 0; t < 3; ++t) cs += wb[i][t];
        const float c3s = c30 + c31 + c32;

        stats_ws[(0 * REPN + r) * BATCH + b] = fmaf(cs, SXf, e1);
        stats_ws[(1 * REPN + r) * BATCH + b] = sq1 + e1q;
        stats_ws[(2 * REPN + r) * BATCH + b] = fmaf(cs, SXf, e2);  // sum(c2)==sum(c1)
        stats_ws[(3 * REPN + r) * BATCH + b] = sq2 + e2q;
        stats_ws[(4 * REPN + r) * BATCH + b] = fmaf(c3s, SXf, e3);
        stats_ws[(5 * REPN + r) * BATCH + b] = sq3 + e3q;
    }
}

// ===========================================================================
// Pass 2 (R14) — half-row per wave (8 rounds each, 2x waves), keeping R13's
// two-window pipeline within each half. Rounds are independent (each loads
// its own 80B window) so the split is mechanically safe.
// ===========================================================================
__device__ __forceinline__ void load_fast(const float* __restrict__ row, int e, float* v) {
    const f32x4* q4 = (const f32x4*)(row + e - 8);
#pragma unroll
    for (int t = 0; t < 5; ++t) {
        f32x4 u = q4[t];
        v[4 * t] = u.x; v[4 * t + 1] = u.y; v[4 * t + 2] = u.z; v[4 * t + 3] = u.w;
    }
}

__device__ __forceinline__ void load_slow(const float* __restrict__ row, int e, float* v) {
#pragma unroll
    for (int d = 0; d < 20; ++d) {
        int fi = e - 8 + d;
        v[d] = ((unsigned)fi < (unsigned)LEN) ? row[fi] : 0.f;
    }
}

__global__ __launch_bounds__(256) void pass2_kernel(const float* __restrict__ x,
                                                    const float* __restrict__ w1,
                                                    const float* __restrict__ w2,
                                                    const float* __restrict__ stats_ws,
                                                    const float* __restrict__ g1, const float* __restrict__ b1,
                                                    const float* __restrict__ g2, const float* __restrict__ b2,
                                                    const float* __restrict__ g3, const float* __restrict__ b3,
                                                    float* __restrict__ out) {
    const int wv = (blockIdx.x << 2) | (threadIdx.x >> 6);
    const int lane = threadIdx.x & 63;
    const int rowid = wv >> 1;
    const int half = wv & 1;
    const int r = rowid % REPN;
    const int b = rowid / REPN;
    const int ch = d_tab.rep[r];
    const float* row = x + ((size_t)b * CH + ch) * LEN;

    // BN finalize: lanes load the 32 batch partials (dup across halves), butterfly.
    float p[6];
    const int bb = lane & 31;
#pragma unroll
    for (int q = 0; q < 6; ++q) p[q] = stats_ws[(q * REPN + r) * BATCH + bb];
#pragma unroll
    for (int m = 1; m < 32; m <<= 1)
#pragma unroll
        for (int q = 0; q < 6; ++q) p[q] += __shfl_xor(p[q], m);

    const double invN = 1.0 / (double)(BATCH * LEN);
    float sc[3], sh[3];
    {
        const float gr[3] = {g1[r], g2[r], g3[r]};
        const float br[3] = {b1[r], b2[r], b3[r]};
#pragma unroll
        for (int q = 0; q < 3; ++q) {
            double mean = (double)p[2 * q] * invN;
            double var = (double)p[2 * q + 1] * invN - mean * mean;
            double inv = 1.0 / sqrt(var + 1e-5);
            double scale = (double)gr[q] * inv;
            sc[q] = (float)scale;
            sh[q] = (float)((double)br[q] - mean * scale);
        }
    }
    const float base = sh[0] + sh[1] + sh[2];

    float wb[5][3];
    const float* p1 = w1 + r * 15;
    const float* p2 = w2 + r * 15;
#pragma unroll
    for (int i = 0; i < 5; ++i)
#pragma unroll
        for (int t = 0; t < 3; ++t) wb[i][t] = p1[i * 3 + t] + p2[i * 3 + t];

    // Combined 15-tap filter (interior): tap d=3k+t applies to v[j+1+d].
    float c[15];
#pragma unroll
    for (int k = 0; k < 5; ++k)
#pragma unroll
        for (int t = 0; t < 3; ++t)
            c[3 * k + t] = fmaf(sc[0], wb[k][t], sc[1] * wb[4 - k][t]);
#pragma unroll
    for (int t = 0; t < 3; ++t) c[6 + t] = fmaf(sc[2], wb[2][t], c[6 + t]);

    float* orow = out + ((size_t)b * CH + r) * LEN;
    float vA[20], vB[20];

#define INTERIOR_QUAD(E, V)                                                       \
    {                                                                             \
        float o[4];                                                               \
        _Pragma("unroll")                                                         \
        for (int j = 0; j < 4; ++j) {                                             \
            float acc = base + V[j + 8];                                          \
            _Pragma("unroll")                                                     \
            for (int d = 0; d < 15; ++d) acc = fmaf(c[d], V[j + 1 + d], acc);     \
            o[j] = acc;                                                           \
        }                                                                         \
        f32x4 t = {o[0], o[1], o[2], o[3]};                                       \
        *(f32x4*)(orow + (E)) = t;                                                \
    }

#define EDGE_QUAD(E, V)                                                           \
    {                                                                             \
        float o[4];                                                               \
        _Pragma("unroll")                                                         \
        for (int j = 0; j < 4; ++j) {                                             \
            const int l = (E) + j;                                                \
            float x1 = 0.f, x2 = 0.f, x3 = 0.f;                                   \
            _Pragma("unroll")                                                     \
            for (int i = 0; i < 5; ++i) {                                         \
                float a1 = fmaf(wb[i][0], V[j + 1 + 3 * i],                       \
                           fmaf(wb[i][1], V[j + 2 + 3 * i],                       \
                                wb[i][2] * V[j + 3 + 3 * i]));                    \
                float a2 = fmaf(wb[i][0], V[j + 13 - 3 * i],                      \
                           fmaf(wb[i][1], V[j + 14 - 3 * i],                      \
                                wb[i][2] * V[j + 15 - 3 * i]));                   \
                if (i == 2) x3 = a1;                                              \
                a1 = ((unsigned)(l - 6 + 3 * i) < (unsigned)LEN) ? a1 : 0.f;      \
                a2 = ((unsigned)(l + 6 - 3 * i) < (unsigned)LEN) ? a2 : 0.f;      \
                x1 += a1; x2 += a2;                                               \
            }                                                                     \
            o[j] = fmaf(sc[0], x1, fmaf(sc[1], x2, fmaf(sc[2], x3, base + V[j + 8]))); \
        }                                                                         \
        f32x4 t = {o[0], o[1], o[2], o[3]};                                       \
        *(f32x4*)(orow + (E)) = t;                                                \
    }

    if (half == 0) {
        { // k = 0 (edge lanes 0,1)
            const int e = 4 * lane;
            if (lane < 2) { load_slow(row, e, vA); EDGE_QUAD(e, vA); }
            else          { load_fast(row, e, vA); INTERIOR_QUAD(e, vA); }
        }
        // k = 1..7, two-window pipeline
        load_fast(row, 4 * lane + 256, vA);
#pragma unroll
        for (int kk = 0; kk < 3; ++kk) {
            const int k = 1 + 2 * kk;
            const int eA = 4 * lane + 256 * k;
            const int eB = eA + 256;
            load_fast(row, eB, vB);
            INTERIOR_QUAD(eA, vA);
            load_fast(row, eB + 256, vA);   // k+2 <= 7
            INTERIOR_QUAD(eB, vB);
        }
        INTERIOR_QUAD(4 * lane + 256 * 7, vA);  // k = 7
    } else {
        // k = 8..14, two-window pipeline
        load_fast(row, 4 * lane + 256 * 8, vA);
#pragma unroll
        for (int kk = 0; kk < 3; ++kk) {
            const int k = 8 + 2 * kk;
            const int eA = 4 * lane + 256 * k;
            const int eB = eA + 256;
            load_fast(row, eB, vB);
            INTERIOR_QUAD(eA, vA);
            load_fast(row, eB + 256, vA);   // k+2 <= 14
            INTERIOR_QUAD(eB, vB);
        }
        INTERIOR_QUAD(4 * lane + 256 * 14, vA); // k = 14
        { // k = 15 (edge lanes 62,63)
            const int e = 4 * lane + 3840;
            if (lane >= 62) { load_slow(row, e, vA); EDGE_QUAD(e, vA); }
            else            { load_fast(row, e, vA); INTERIOR_QUAD(e, vA); }
        }
    }
#undef INTERIOR_QUAD
#undef EDGE_QUAD
}

extern "C" void kernel_launch(void* const* d_in, const int* in_sizes, int n_in,
                              void* d_out, int out_size, void* d_ws, size_t ws_size,
                              hipStream_t stream) {
    const float* x  = (const float*)d_in[0];
    const float* w1 = (const float*)d_in[1];
    const float* w2 = (const float*)d_in[2];
    const float* g1 = (const float*)d_in[3];
    const float* b1 = (const float*)d_in[4];
    const float* g2 = (const float*)d_in[5];
    const float* b2 = (const float*)d_in[6];
    const float* g3 = (const float*)d_in[7];
    const float* b3 = (const float*)d_in[8];
    float* out = (float*)d_out;
    float* stats_ws = (float*)d_ws;   // 6*198*32 floats = 152 KB

    // pass1: 3168 rep-stats blocks (half-row waves) + 1856 ghost blocks.
    pass1_kernel<<<P1REPBLK + NGHOST, 256, 0, stream>>>(x, w1, w2, stats_ws, out);
    // pass2: 12672 half-row waves = 3168 blocks.
    pass2_kernel<<<P2REPBLK, 256, 0, stream>>>(x, w1, w2, stats_ws,
                                               g1, b1, g2, b2, g3, b3, out);
}